// Round 10
// baseline (3830.257 us; speedup 1.0000x reference)
//
#include <hip/hip_runtime.h>
#include <stdint.h>

#define VOCAB 50257
#define B 256
#define EMB 300
#define HID 700
#define G3 2100          // 3*HID
#define ZDIM 500
#define ATTR_EMBD 200
#define MAXLEN 30
#define SEQ 31           // MAXLEN+1
#define HY_ELEMS (B*SEQ*HID)
#define KP 704           // HID padded to mult of 32
#define NKT 22           // KP/32 k-tiles
#define KIH 320          // EMB padded to mult of 32
#define VPAD 50304       // VOCAB padded to mult of 128 (393*128)
#define NVT 393          // VPAD/128
#define MPAD 2112        // G3 padded to 33*64
#define SOS_IDX 1
#define EOS_IDX 2
// tiled chunk: per (tile, kt): [part(2)][4096 halves]; half idx = (kc*128+row)*8+e
#define CHUNK 4096
#define TILE_STRIDE ((size_t)NKT * 2 * CHUNK)   // halves per v-panel / h half-tile
// logits grid: items = (panel, v-half, b-half) = 393*2*2 = 1572; 8 XCD x 197
#define NIT5 1572
#define NBLK5 1576

typedef _Float16 half8 __attribute__((ext_vector_type(8)));
typedef _Float16 half4 __attribute__((ext_vector_type(4)));
typedef float f32x4 __attribute__((ext_vector_type(4)));

// ---------------- global_load_lds helper (16B per lane, dest = wave base + lane*16)
typedef const __attribute__((address_space(1))) void* gas1_t;
typedef __attribute__((address_space(3))) void* las3_t;
__device__ __forceinline__ void gload_lds16(const void* g, void* l) {
  __builtin_amdgcn_global_load_lds((gas1_t)g, (las3_t)l, 16, 0, 0);
}

// ---------------- threefry2x32 (JAX-exact, 20 rounds) ----------------
__device__ __forceinline__ uint32_t rotl32(uint32_t x, int r) {
  return (x << r) | (x >> (32 - r));
}

__device__ __forceinline__ void threefry2x32(uint32_t k0, uint32_t k1,
                                             uint32_t x0, uint32_t x1,
                                             uint32_t& o0, uint32_t& o1) {
  const uint32_t ks2 = k0 ^ k1 ^ 0x1BD11BDAu;
  x0 += k0; x1 += k1;
#define TF_R4(a, b, c, d)                                     \
  x0 += x1; x1 = rotl32(x1, a); x1 ^= x0;                     \
  x0 += x1; x1 = rotl32(x1, b); x1 ^= x0;                     \
  x0 += x1; x1 = rotl32(x1, c); x1 ^= x0;                     \
  x0 += x1; x1 = rotl32(x1, d); x1 ^= x0;
  TF_R4(13, 15, 26, 6)  x0 += k1;  x1 += ks2 + 1u;
  TF_R4(17, 29, 16, 24) x0 += ks2; x1 += k0 + 2u;
  TF_R4(13, 15, 26, 6)  x0 += k0;  x1 += k1 + 3u;
  TF_R4(17, 29, 16, 24) x0 += k1;  x1 += ks2 + 4u;
  TF_R4(13, 15, 26, 6)  x0 += ks2; x1 += k0 + 5u;
#undef TF_R4
  o0 = x0; o1 = x1;
}

__device__ __forceinline__ unsigned long long gumbel_pack(float s, uint32_t key0,
                                                          uint32_t key1, int b, int v) {
  uint32_t j = (uint32_t)(b * VOCAB + v);
  uint32_t o0, o1;
  threefry2x32(key0, key1, 0u, j, o0, o1);
  uint32_t bits = o0 ^ o1;
  float f = __uint_as_float((bits >> 9) | 0x3f800000u) - 1.0f;
  float u = fmaxf(f, 1.17549435e-38f);
  float g = -__logf(-__logf(u));
  s += g;
  uint32_t us = __float_as_uint(s);
  us = (us & 0x80000000u) ? ~us : (us | 0x80000000u);
  return ((unsigned long long)us << 32) | (uint32_t)(~(uint32_t)v);
}

// split helper: val*scale -> {fp16 hi, fp16 lo = raw residual (UNSCALED)}.
// Unscaled lo lets hi*hi + hi*lo + lo*hi accumulate into ONE accumulator.
struct hl16 { _Float16 hi, lo; };
__device__ __forceinline__ hl16 split16(float val, float scale) {
  float s = val * scale;
  _Float16 h = (_Float16)s;
  hl16 r;
  r.hi = h;
  r.lo = (_Float16)(s - (float)h);
  return r;
}

// ---------------- init ----------------
__global__ void k_init(const float* __restrict__ z, const int* __restrict__ l,
                       const float* __restrict__ attr_w, const float* __restrict__ emb_w,
                       float* __restrict__ hbuf0, uint32_t* __restrict__ keys,
                       unsigned long long* __restrict__ slots,
                       int* __restrict__ tok, float* __restrict__ y_out,
                       _Float16* __restrict__ h_hi, _Float16* __restrict__ h_lo,
                       _Float16* __restrict__ ht,
                       _Float16* __restrict__ x0_hi, _Float16* __restrict__ x0_lo,
                       _Float16* __restrict__ xe_hi, _Float16* __restrict__ xe_lo,
                       int full) {
  int idx = blockIdx.x * blockDim.x + threadIdx.x;
  if (idx < B * HID) {
    int b = idx / HID, i = idx % HID;
    float v = (i < ZDIM) ? z[b * ZDIM + i]
                         : attr_w[l[b] * ATTR_EMBD + (i - ZDIM)];
    hbuf0[idx] = v;
    hl16 r = split16(v, 8.0f);
    h_hi[b * KP + i] = r.hi;
    h_lo[b * KP + i] = r.lo;
  }
  if (idx < MAXLEN) {
    uint32_t o0, o1;
    threefry2x32(0u, 42u, 0u, (uint32_t)idx, o0, o1);
    keys[2 * idx] = o0; keys[2 * idx + 1] = o1;
  }
  if (idx < MAXLEN * B) slots[idx] = 0ull;
  if (idx < B) {
    tok[idx] = SOS_IDX;
    tok[31 * B + idx] = EOS_IDX;
    y_out[idx * SEQ + MAXLEN] = 2.0f;
  }
  if (idx < B * 4) {  // zero k-pad (700..703) of linear + tiled h (kt=21, kc=3)
    int b = idx >> 2, k = HID + (idx & 3);
    h_hi[b * KP + k] = (_Float16)0.0f;
    h_lo[b * KP + k] = (_Float16)0.0f;
    int c = b >> 7, row = b & 127, e = k & 7;
    size_t tb = (size_t)c * TILE_STRIDE + (size_t)21 * 2 * CHUNK
              + (3 * 128 + row) * 8 + e;
    ht[tb] = (_Float16)0.0f;
    ht[tb + CHUNK] = (_Float16)0.0f;
  }
  if (full && idx < KIH) {
    float v0 = (idx < EMB) ? emb_w[SOS_IDX * EMB + idx] : 0.0f;
    float ve = (idx < EMB) ? emb_w[EOS_IDX * EMB + idx] : 0.0f;
    hl16 r0 = split16(v0, 8.0f);
    hl16 re = split16(ve, 8.0f);
    for (int b = 0; b < B; ++b) {  // broadcast rows (all batches share SOS/EOS)
      x0_hi[b * KIH + idx] = r0.hi; x0_lo[b * KIH + idx] = r0.lo;
      xe_hi[b * KIH + idx] = re.hi; xe_lo[b * KIH + idx] = re.lo;
    }
  }
}

// ---------------- logits w split -> TILED fragment-image layout ----------------
__global__ void k_wsplit(const float* __restrict__ out_w, _Float16* __restrict__ wt) {
  size_t idx = (size_t)blockIdx.x * blockDim.x + threadIdx.x;
  if (idx >= (size_t)NVT * NKT * 1024) return;
  int h4 = (int)(idx & 1023);
  int ktp = (int)(idx >> 10);
  int kt = ktp % NKT, p = ktp / NKT;
  int slot4 = h4 >> 1, e0 = (h4 & 1) * 4;
  int kc = slot4 >> 7, row = slot4 & 127;
  int v = p * 128 + row;
  int k = kt * 32 + kc * 8 + e0;
  float x[4];
  if (v < VOCAB && k + 3 < HID) {
    const float4 xv = *(const float4*)&out_w[(size_t)v * HID + k];
    x[0] = xv.x; x[1] = xv.y; x[2] = xv.z; x[3] = xv.w;
  } else {
#pragma unroll
    for (int j = 0; j < 4; ++j)
      x[j] = (v < VOCAB && k + j < HID) ? out_w[(size_t)v * HID + k + j] : 0.0f;
  }
  half4 hi, lo;
#pragma unroll
  for (int j = 0; j < 4; ++j) {
    hl16 r = split16(x[j], 64.0f);
    hi[j] = r.hi; lo[j] = r.lo;
  }
  size_t base = (size_t)p * TILE_STRIDE + (size_t)kt * 2 * CHUNK + slot4 * 8 + e0;
  *(half4*)&wt[base] = hi;
  *(half4*)&wt[base + CHUNK] = lo;
}

// ---------------- generic gate-weight split (Msrc x Ksrc -> MPAD x Kpad) ----------------
__global__ void k_gwsplit(const float* __restrict__ src, _Float16* __restrict__ hi,
                          _Float16* __restrict__ lo, int Msrc, int Ksrc, int Kpad,
                          int tot4) {
  int idx = blockIdx.x * blockDim.x + threadIdx.x;
  if (idx >= tot4) return;
  size_t i4 = (size_t)idx * 4;
  int m = (int)(i4 / Kpad), k = (int)(i4 % Kpad);
  half4 h, l;
#pragma unroll
  for (int j = 0; j < 4; ++j) {
    float x = (m < Msrc && k + j < Ksrc) ? src[(size_t)m * Ksrc + k + j] : 0.0f;
    hl16 r = split16(x, 64.0f);
    h[j] = r.hi; l[j] = r.lo;
  }
  *(half4*)&hi[i4] = h;
  *(half4*)&lo[i4] = l;
}

// ---------------- MFMA gates: 64j x 64b blocks, 4 waves (32x32), merged acc ----
__global__ __launch_bounds__(256, 4)
void k_gates2(const _Float16* __restrict__ wih_hi, const _Float16* __restrict__ wih_lo,
              const _Float16* __restrict__ whh_hi, const _Float16* __restrict__ whh_lo,
              const _Float16* __restrict__ x_hi, const _Float16* __restrict__ x_lo,
              const _Float16* __restrict__ h_hi, const _Float16* __restrict__ h_lo,
              float* __restrict__ gi, float* __restrict__ gh) {
  const int zz = blockIdx.z;
  const _Float16* __restrict__ Whi = zz ? whh_hi : wih_hi;
  const _Float16* __restrict__ Wlo = zz ? whh_lo : wih_lo;
  const _Float16* __restrict__ Xhi = zz ? h_hi : x_hi;
  const _Float16* __restrict__ Xlo = zz ? h_lo : x_lo;
  const int Kz = zz ? KP : KIH;
  float* __restrict__ out = zz ? gh : gi;

  const int jbase = blockIdx.x * 64;
  const int bbase = blockIdx.y * 64;
  __shared__ float4 lds[2][4][256];   // [buf][whi,wlo,xhi,xlo][kc*64+row]
  const int tid = threadIdx.x, lane = tid & 63, wid = tid >> 6;
  const int wj = wid >> 1, wb2 = wid & 1;
  const size_t wrow = (size_t)(jbase + lane) * Kz;   // stage: kc=wid, row=lane
  const size_t xrow = (size_t)(bbase + lane) * Kz;

  f32x4 acc[2][2];
#pragma unroll
  for (int i = 0; i < 2; ++i)
#pragma unroll
    for (int j = 0; j < 2; ++j) acc[i][j] = (f32x4)0.0f;

#define GSTAGE(bf, k0)                                                   \
  {                                                                      \
    gload_lds16(Whi + wrow + (k0) + wid * 8, &lds[bf][0][wid * 64]);     \
    gload_lds16(Wlo + wrow + (k0) + wid * 8, &lds[bf][1][wid * 64]);     \
    gload_lds16(Xhi + xrow + (k0) + wid * 8, &lds[bf][2][wid * 64]);     \
    gload_lds16(Xlo + xrow + (k0) + wid * 8, &lds[bf][3][wid * 64]);     \
  }

  const int nt = Kz / 32;
  GSTAGE(0, 0)
  for (int kt = 0; kt < nt; ++kt) {
    const int cur = kt & 1;
    __syncthreads();                       // drains staged loads for buf[cur]
    if (kt + 1 < nt) GSTAGE(cur ^ 1, (kt + 1) * 32)
    const int kcf = (lane >> 4) * 64 + (lane & 15);
    half8 a_hi[2], a_lo[2];
#pragma unroll
    for (int fv = 0; fv < 2; ++fv) {
      int s = kcf + wj * 32 + fv * 16;
      a_hi[fv] = *(const half8*)&lds[cur][0][s];
      a_lo[fv] = *(const half8*)&lds[cur][1][s];
    }
#pragma unroll
    for (int fb = 0; fb < 2; ++fb) {
      int s = kcf + wb2 * 32 + fb * 16;
      half8 b_hi = *(const half8*)&lds[cur][2][s];
      half8 b_lo = *(const half8*)&lds[cur][3][s];
#pragma unroll
      for (int fv = 0; fv < 2; ++fv) {
        acc[fv][fb] = __builtin_amdgcn_mfma_f32_16x16x32_f16(a_hi[fv], b_hi,
                                                             acc[fv][fb], 0, 0, 0);
        acc[fv][fb] = __builtin_amdgcn_mfma_f32_16x16x32_f16(a_hi[fv], b_lo,
                                                             acc[fv][fb], 0, 0, 0);
        acc[fv][fb] = __builtin_amdgcn_mfma_f32_16x16x32_f16(a_lo[fv], b_hi,
                                                             acc[fv][fb], 0, 0, 0);
      }
    }
  }
#undef GSTAGE

  const float c2 = 1.0f / 512.0f;
#pragma unroll
  for (int fb = 0; fb < 2; ++fb) {
    const int b = bbase + wb2 * 32 + fb * 16 + (lane & 15);
#pragma unroll
    for (int fv = 0; fv < 2; ++fv) {
#pragma unroll
      for (int r = 0; r < 4; ++r) {
        int j = jbase + wj * 32 + fv * 16 + (lane >> 4) * 4 + r;
        if (j < G3) out[b * G3 + j] = acc[fv][fb][r] * c2;
      }
    }
  }
}

// ---------------- fp32 gates fallback ----------------
__global__ void k_gates(const float* __restrict__ W_ih, const float* __restrict__ W_hh,
                        const float* __restrict__ emb_w, const float* __restrict__ hprev,
                        const int* __restrict__ tok,
                        float* __restrict__ gi, float* __restrict__ gh) {
  const int zz = blockIdx.z;
  const float* __restrict__ W = zz ? W_hh : W_ih;
  const int K = zz ? HID : EMB;
  float* __restrict__ out = zz ? gh : gi;
  __shared__ float w_lds[20][36];
  __shared__ float xh_lds[20][36];
  const int jbase = blockIdx.x * 32;
  const int bbase = blockIdx.y * 32;
  const int tid = threadIdx.x;
  const int tj = tid % 16, tb = tid / 16;
  float a00 = 0.f, a01 = 0.f, a10 = 0.f, a11 = 0.f;
  for (int k0 = 0; k0 < K; k0 += 20) {
    for (int idx = tid; idx < 640; idx += 256) {
      int col = idx / 20, kk = idx % 20;
      int j = jbase + col;
      w_lds[kk][col] = (j < G3) ? W[j * K + k0 + kk] : 0.0f;
      int b = bbase + col;
      float xv;
      if (zz) xv = hprev[b * HID + k0 + kk];
      else    xv = emb_w[tok[b] * EMB + k0 + kk];
      xh_lds[kk][col] = xv;
    }
    __syncthreads();
#pragma unroll
    for (int kk = 0; kk < 20; ++kk) {
      float w0 = w_lds[kk][tj * 2], w1 = w_lds[kk][tj * 2 + 1];
      float h0 = xh_lds[kk][tb * 2], h1 = xh_lds[kk][tb * 2 + 1];
      a00 += w0 * h0; a01 += w0 * h1;
      a10 += w1 * h0; a11 += w1 * h1;
    }
    __syncthreads();
  }
  int j0 = jbase + tj * 2, b0 = bbase + tb * 2;
  if (j0 < G3)     { out[b0 * G3 + j0] = a00;     out[(b0 + 1) * G3 + j0] = a01; }
  if (j0 + 1 < G3) { out[b0 * G3 + j0 + 1] = a10; out[(b0 + 1) * G3 + j0 + 1] = a11; }
}

// ---------------- pointwise GRU update + h fp16-split (linear for gates, tiled for logits)
__global__ void k_hnew(const float* __restrict__ gi, const float* __restrict__ gh,
                       const float* __restrict__ b_ih, const float* __restrict__ b_hh,
                       const float* __restrict__ hprev, float* __restrict__ hnext,
                       float* __restrict__ hy, _Float16* __restrict__ h_hi,
                       _Float16* __restrict__ h_lo, _Float16* __restrict__ ht, int t) {
  int idx = blockIdx.x * blockDim.x + threadIdx.x;
  if (idx >= B * HID) return;
  int b = idx / HID, i = idx % HID;
  float ir = gi[b * G3 + i]            + b_ih[i];
  float iz = gi[b * G3 + HID + i]      + b_ih[HID + i];
  float in_ = gi[b * G3 + 2 * HID + i] + b_ih[2 * HID + i];
  float hr = gh[b * G3 + i]            + b_hh[i];
  float hz = gh[b * G3 + HID + i]      + b_hh[HID + i];
  float hn = gh[b * G3 + 2 * HID + i]  + b_hh[2 * HID + i];
  float r  = 1.0f / (1.0f + expf(-(ir + hr)));
  float zg = 1.0f / (1.0f + expf(-(iz + hz)));
  float n  = tanhf(in_ + r * hn);
  float h  = (1.0f - zg) * n + zg * hprev[idx];
  hnext[idx] = h;
  hy[(size_t)b * SEQ * HID + (size_t)t * HID + i] = h;
  hl16 rr = split16(h, 8.0f);
  h_hi[b * KP + i] = rr.hi;
  h_lo[b * KP + i] = rr.lo;
  // tiled image for k_logits6: c=b>>7 (128-row halves), row=b&127,
  // kt=i>>5, kc=(i>>3)&3, e=i&7
  int c = b >> 7, row = b & 127;
  size_t tb = (size_t)c * TILE_STRIDE + (size_t)(i >> 5) * 2 * CHUNK
            + ((((i >> 3) & 3) * 128 + row) * 8) + (i & 7);
  ht[tb] = rr.hi;
  ht[tb + CHUNK] = rr.lo;
}

// ---------------- MFMA logits v7: ALL-REGISTER, no LDS, NO BARRIERS ----
// 32v x 64b wave tiles (merged acc = 32 VGPR), block = 4 waves over 64v x 128b.
// Every lane's fragment is one contiguous 16B slot of the tiled images ->
// direct global_load_dwordx4 to VGPRs. w double-buffered one kt ahead; h
// single-buffered (L2-hot; 4 waves/SIMD TLP hides it). Nothing ever drains
// vmcnt block-wide -- the r9 per-kt barrier stall is structurally gone.
__global__ __launch_bounds__(256, 4)
void k_logits6(const _Float16* __restrict__ wt, const _Float16* __restrict__ ht,
               const float* __restrict__ out_b, const uint32_t* __restrict__ keys,
               unsigned long long* __restrict__ slot, int t) {
  const int item = (blockIdx.x & 7) * 197 + (blockIdx.x >> 3);  // XCD-chunked
  if (item >= NIT5) return;
  const int p = item >> 2, vh = (item >> 1) & 1, c = item & 1;

  const int tid = threadIdx.x, lane = tid & 63, wid = tid >> 6;
  const int wv = wid >> 1, wb = wid & 1;
  const int lq = lane >> 4, lr = lane & 15;

  const _Float16* __restrict__ wp = wt + (size_t)p * TILE_STRIDE;
  const _Float16* __restrict__ hp = ht + (size_t)c * TILE_STRIDE;

  const int wslot = lq * 128 + vh * 64 + wv * 32 + lr;   // + fv*16
  const int hslot = lq * 128 + wb * 64 + lr;             // + fb*16

  f32x4 acc[2][4];
#pragma unroll
  for (int i = 0; i < 2; ++i)
#pragma unroll
    for (int j = 0; j < 4; ++j) acc[i][j] = (f32x4)0.0f;

  half8 wA[4], wB[4];   // [fv*2 + part]
  half8 hC[8];          // [fb*2 + part]

#define LOADW(W, ktv)                                                         \
  {                                                                           \
    const _Float16* bw = wp + (size_t)(ktv) * (2 * CHUNK);                    \
    _Pragma("unroll")                                                         \
    for (int fv = 0; fv < 2; ++fv) {                                          \
      W[fv * 2 + 0] = *(const half8*)(bw + (wslot + fv * 16) * 8);            \
      W[fv * 2 + 1] = *(const half8*)(bw + CHUNK + (wslot + fv * 16) * 8);    \
    }                                                                         \
  }
#define LOADH(ktv)                                                            \
  {                                                                           \
    const _Float16* bh = hp + (size_t)(ktv) * (2 * CHUNK);                    \
    _Pragma("unroll")                                                         \
    for (int fb = 0; fb < 4; ++fb) {                                          \
      hC[fb * 2 + 0] = *(const half8*)(bh + (hslot + fb * 16) * 8);           \
      hC[fb * 2 + 1] = *(const half8*)(bh + CHUNK + (hslot + fb * 16) * 8);   \
    }                                                                         \
  }
#define MFMAB(W)                                                              \
  _Pragma("unroll")                                                           \
  for (int fb = 0; fb < 4; ++fb) {                                            \
    _Pragma("unroll")                                                         \
    for (int fv = 0; fv < 2; ++fv) {                                          \
      acc[fv][fb] = __builtin_amdgcn_mfma_f32_16x16x32_f16(                   \
          W[fv * 2 + 0], hC[fb * 2 + 0], acc[fv][fb], 0, 0, 0);               \
      acc[fv][fb] = __builtin_amdgcn_mfma_f32_16x16x32_f16(                   \
          W[fv * 2 + 0], hC[fb * 2 + 1], acc[fv][fb], 0, 0, 0);               \
      acc[fv][fb] = __builtin_amdgcn_mfma_f32_16x16x32_f16(                   \
          W[fv * 2 + 1], hC[fb * 2 + 0], acc[fv][fb], 0, 0, 0);               \
    }                                                                         \
  }

  LOADW(wA, 0)
  // NKT = 22 (even): 2x-unrolled; w one kt ahead, h per-kt (WAR on hC keeps
  // loads behind the consuming MFMAs' issue -- compiler interleaves).
#pragma unroll 1
  for (int kt = 0; kt < NKT; kt += 2) {
    LOADH(kt)
    LOADW(wB, kt + 1)
    MFMAB(wA)
    LOADH(kt + 1)
    if (kt + 2 < NKT) LOADW(wA, kt + 2)
    MFMAB(wB)
  }
#undef LOADW
#undef LOADH
#undef MFMAB

  const uint32_t key0 = keys[2 * t], key1 = keys[2 * t + 1];
  const float c2 = 1.0f / 512.0f;
  const int vbase0 = p * 128 + vh * 64 + wv * 32;
#pragma unroll
  for (int fb = 0; fb < 4; ++fb) {
    const int b = c * 128 + wb * 64 + fb * 16 + lr;
    unsigned long long best = 0ull;
#pragma unroll
    for (int fv = 0; fv < 2; ++fv) {
#pragma unroll
      for (int r = 0; r < 4; ++r) {
        int v = vbase0 + fv * 16 + lq * 4 + r;
        if (v < VOCAB) {
          float s = acc[fv][fb][r] * c2 + out_b[v];
          unsigned long long cand = gumbel_pack(s, key0, key1, b, v);
          if (cand > best) best = cand;
        }
      }
    }
    unsigned long long o;
    o = __shfl_xor(best, 16, 64); if (o > best) best = o;
    o = __shfl_xor(best, 32, 64); if (o > best) best = o;
    if (lq == 0) atomicMax(&slot[b], best);
  }
}

// ---------------- fp32 logits fallback ----------------
#define WPITCH 68
#define HPITCH 260
__global__ __launch_bounds__(256)
void k_logits_f32(const float* __restrict__ h, const float* __restrict__ out_w,
                  const float* __restrict__ out_b, const uint32_t* __restrict__ keys,
                  unsigned long long* __restrict__ slot, int t) {
  __shared__ float w_lds[20][WPITCH];
  __shared__ float h_lds[20][HPITCH];
  const int vbase = blockIdx.x * 64;
  const int tid = threadIdx.x;
  const int tv = tid % 8, tb = tid / 8;
  float acc[8][8];
#pragma unroll
  for (int i = 0; i < 8; ++i)
#pragma unroll
    for (int j = 0; j < 8; ++j) acc[i][j] = 0.f;

  for (int k0 = 0; k0 < HID; k0 += 20) {
    for (int idx = tid; idx < 64 * 20; idx += 256) {
      int vv = idx / 20, kk = idx % 20;
      int v = vbase + vv;
      w_lds[kk][vv] = (v < VOCAB) ? out_w[(size_t)v * HID + k0 + kk] : 0.0f;
    }
    for (int idx = tid; idx < 256 * 20; idx += 256) {
      int bb = idx / 20, kk = idx % 20;
      h_lds[kk][bb] = h[bb * HID + k0 + kk];
    }
    __syncthreads();
#pragma unroll
    for (int kk = 0; kk < 20; ++kk) {
      float wv[8], hv[8];
      *(float4*)&wv[0] = *(const float4*)&w_lds[kk][tv * 8];
      *(float4*)&wv[4] = *(const float4*)&w_lds[kk][tv * 8 + 4];
      *(float4*)&hv[0] = *(const float4*)&h_lds[kk][tb * 8];
      *(float4*)&hv[4] = *(const float4*)&h_lds[kk][tb * 8 + 4];
#pragma unroll
      for (int iv = 0; iv < 8; ++iv)
#pragma unroll
        for (int ib = 0; ib < 8; ++ib) acc[iv][ib] += wv[iv] * hv[ib];
    }
    __syncthreads();
  }

  const uint32_t key0 = keys[2 * t], key1 = keys[2 * t + 1];
#pragma unroll
  for (int ib = 0; ib < 8; ++ib) {
    const int b = tb * 8 + ib;
    unsigned long long best = 0ull;
#pragma unroll
    for (int iv = 0; iv < 8; ++iv) {
      int v = vbase + tv * 8 + iv;
      if (v >= VOCAB) continue;
      unsigned long long cand = gumbel_pack(acc[iv][ib] + out_b[v], key0, key1, b, v);
      if (cand > best) best = cand;
    }
#pragma unroll
    for (int off = 1; off < 8; off <<= 1) {
      unsigned long long other = __shfl_xor(best, off, 64);
      if (other > best) best = other;
    }
    if (tv == 0) atomicMax(&slot[b], best);
  }
}

// ---------------- token extraction + emb gather/split ----------------
__global__ void k_tok2(const unsigned long long* __restrict__ slot,
                       const float* __restrict__ emb_w,
                       int* __restrict__ tok_next, float* __restrict__ y_out,
                       _Float16* __restrict__ xc_hi, _Float16* __restrict__ xc_lo,
                       int t, int full) {
  const int b = blockIdx.x;
  const int c = threadIdx.x;   // 128 threads
  unsigned long long p = slot[b];
  uint32_t v = ~((uint32_t)(p & 0xFFFFFFFFull));
  if (c == 0) {
    tok_next[b] = (int)v;
    y_out[b * SEQ + t] = (float)v;
  }
  if (!full) return;
  if (c < 75) {
    float4 xv = *(const float4*)&emb_w[(size_t)v * EMB + c * 4];
    half4 hi, lo;
    hl16 r0 = split16(xv.x, 8.0f); hi[0] = r0.hi; lo[0] = r0.lo;
    hl16 r1 = split16(xv.y, 8.0f); hi[1] = r1.hi; lo[1] = r1.lo;
    hl16 r2 = split16(xv.z, 8.0f); hi[2] = r2.hi; lo[2] = r2.lo;
    hl16 r3 = split16(xv.w, 8.0f); hi[3] = r3.hi; lo[3] = r3.lo;
    *(half4*)&xc_hi[b * KIH + c * 4] = hi;
    *(half4*)&xc_lo[b * KIH + c * 4] = lo;
  } else if (c < 80) {
    *(half4*)&xc_hi[b * KIH + c * 4] = (half4)(_Float16)0.0f;
    *(half4*)&xc_lo[b * KIH + c * 4] = (half4)(_Float16)0.0f;
  }
}

// ---------------- host launch ----------------
extern "C" void kernel_launch(void* const* d_in, const int* in_sizes, int n_in,
                              void* d_out, int out_size, void* d_ws, size_t ws_size,
                              hipStream_t stream) {
  const float* z      = (const float*)d_in[0];
  const int*   l      = (const int*)  d_in[1];
  const float* emb_w  = (const float*)d_in[2];
  const float* attr_w = (const float*)d_in[3];
  const float* W_ih   = (const float*)d_in[4];
  const float* W_hh   = (const float*)d_in[5];
  const float* b_ih   = (const float*)d_in[6];
  const float* b_hh   = (const float*)d_in[7];
  const float* out_w  = (const float*)d_in[8];
  const float* out_b  = (const float*)d_in[9];

  float* hy    = (float*)d_out;
  float* y_out = (float*)d_out + HY_ELEMS;

  char* ws = (char*)d_ws;
  size_t off = 0;
  uint32_t* keys            = (uint32_t*)(ws + off);           off += 256;
  unsigned long long* slots = (unsigned long long*)(ws + off); off += (size_t)MAXLEN * B * 8;
  int* tokbuf               = (int*)(ws + off);                off += (size_t)32 * B * 4;
  float* hbuf               = (float*)(ws + off);              off += (size_t)2 * B * HID * 4;
  float* gi                 = (float*)(ws + off);              off += (size_t)B * G3 * 4;
  float* gh                 = (float*)(ws + off);              off += (size_t)B * G3 * 4;
  _Float16* h_hi            = (_Float16*)(ws + off);           off += (size_t)B * KP * 2;
  _Float16* h_lo            = (_Float16*)(ws + off);           off += (size_t)B * KP * 2;
  _Float16* ht              = (_Float16*)(ws + off);           off += (size_t)2 * TILE_STRIDE * 2;
  _Float16* wt              = (_Float16*)(ws + off);           off += (size_t)NVT * TILE_STRIDE * 2;
  const size_t tier1_end = off;
  _Float16* wih_hi          = (_Float16*)(ws + off);           off += (size_t)MPAD * KIH * 2;
  _Float16* wih_lo          = (_Float16*)(ws + off);           off += (size_t)MPAD * KIH * 2;
  _Float16* whh_hi          = (_Float16*)(ws + off);           off += (size_t)MPAD * KP * 2;
  _Float16* whh_lo          = (_Float16*)(ws + off);           off += (size_t)MPAD * KP * 2;
  _Float16* x0_hi           = (_Float16*)(ws + off);           off += (size_t)B * KIH * 2;
  _Float16* x0_lo           = (_Float16*)(ws + off);           off += (size_t)B * KIH * 2;
  _Float16* xe_hi           = (_Float16*)(ws + off);           off += (size_t)B * KIH * 2;
  _Float16* xe_lo           = (_Float16*)(ws + off);           off += (size_t)B * KIH * 2;
  _Float16* xc_hi           = (_Float16*)(ws + off);           off += (size_t)B * KIH * 2;
  _Float16* xc_lo           = (_Float16*)(ws + off);           off += (size_t)B * KIH * 2;
  const size_t tier2_end = off;
  const int tier = (ws_size >= tier2_end) ? 2 : ((ws_size >= tier1_end) ? 1 : 0);

  k_init<<<(B * HID + 255) / 256, 256, 0, stream>>>(
      z, l, attr_w, emb_w, hbuf, keys, slots, tokbuf, y_out, h_hi, h_lo, ht,
      x0_hi, x0_lo, xe_hi, xe_lo, (tier == 2) ? 1 : 0);

  if (tier >= 1) {
    size_t tot = (size_t)NVT * NKT * 1024;
    k_wsplit<<<(int)((tot + 255) / 256), 256, 0, stream>>>(out_w, wt);
  }
  if (tier == 2) {
    int tih = MPAD * KIH / 4, thh = MPAD * KP / 4;
    k_gwsplit<<<(tih + 255) / 256, 256, 0, stream>>>(W_ih, wih_hi, wih_lo, G3, EMB, KIH, tih);
    k_gwsplit<<<(thh + 255) / 256, 256, 0, stream>>>(W_hh, whh_hi, whh_lo, G3, HID, KP, thh);
  }

  for (int t = 0; t <= MAXLEN; ++t) {
    float* hprev = hbuf + (t % 2) * B * HID;
    float* hnext = hbuf + ((t + 1) % 2) * B * HID;

    if (tier == 2) {
      const _Float16* xh = (t == 0) ? x0_hi : ((t == MAXLEN) ? xe_hi : xc_hi);
      const _Float16* xl = (t == 0) ? x0_lo : ((t == MAXLEN) ? xe_lo : xc_lo);
      dim3 g2(33, 4, 2);
      k_gates2<<<g2, 256, 0, stream>>>(wih_hi, wih_lo, whh_hi, whh_lo,
                                       xh, xl, h_hi, h_lo, gi, gh);
    } else {
      const int* tok_t = tokbuf + ((t == MAXLEN) ? 31 : t) * B;
      dim3 ggrid(66, 8, 2);
      k_gates<<<ggrid, 256, 0, stream>>>(W_ih, W_hh, emb_w, hprev, tok_t, gi, gh);
    }
    k_hnew<<<(B * HID + 255) / 256, 256, 0, stream>>>(gi, gh, b_ih, b_hh, hprev,
                                                      hnext, hy, h_hi, h_lo, ht, t);
    if (t < MAXLEN) {
      if (tier >= 1) {
        k_logits6<<<NBLK5, 256, 0, stream>>>(wt, ht, out_b, keys,
                                             slots + (size_t)t * B, t);
      } else {
        k_logits_f32<<<(VOCAB + 63) / 64, 256, 0, stream>>>(hnext, out_w, out_b, keys,
                                                            slots + (size_t)t * B, t);
      }
      k_tok2<<<B, 128, 0, stream>>>(slots + (size_t)t * B, emb_w,
                                    tokbuf + (t + 1) * B, y_out, xc_hi, xc_lo,
                                    t, (tier == 2) ? 1 : 0);
    }
  }
}

// Round 11
// 3738.992 us; speedup vs baseline: 1.0244x; 1.0244x over previous
//
#include <hip/hip_runtime.h>
#include <stdint.h>

#define VOCAB 50257
#define B 256
#define EMB 300
#define HID 700
#define G3 2100          // 3*HID
#define ZDIM 500
#define ATTR_EMBD 200
#define MAXLEN 30
#define SEQ 31           // MAXLEN+1
#define HY_ELEMS (B*SEQ*HID)
#define KP 704           // HID padded to mult of 32
#define NKT 22           // KP/32 k-tiles
#define KIH 320          // EMB padded to mult of 32
#define VPAD 50304       // VOCAB padded to mult of 128 (393*128)
#define NVT 393          // VPAD/128
#define MPAD 2112        // G3 padded to 33*64
#define SOS_IDX 1
#define EOS_IDX 2
// tiled chunk: per (tile, kt): [part(2)][4096 halves]; half idx = (kc*128+row)*8+e
#define CHUNK 4096
#define TILE_STRIDE ((size_t)NKT * 2 * CHUNK)   // halves per v-panel / h half-tile
// logits grid: items = (panel, v-half, b-half) = 393*2*2 = 1572; 8 XCD x 197
#define NIT5 1572
#define NBLK5 1576

typedef _Float16 half8 __attribute__((ext_vector_type(8)));
typedef _Float16 half4 __attribute__((ext_vector_type(4)));
typedef float f32x4 __attribute__((ext_vector_type(4)));

// ---------------- global_load_lds helper (16B per lane, dest = wave base + lane*16)
typedef const __attribute__((address_space(1))) void* gas1_t;
typedef __attribute__((address_space(3))) void* las3_t;
__device__ __forceinline__ void gload_lds16(const void* g, void* l) {
  __builtin_amdgcn_global_load_lds((gas1_t)g, (las3_t)l, 16, 0, 0);
}

// ---------------- threefry2x32 (JAX-exact, 20 rounds) ----------------
__device__ __forceinline__ uint32_t rotl32(uint32_t x, int r) {
  return (x << r) | (x >> (32 - r));
}

__device__ __forceinline__ void threefry2x32(uint32_t k0, uint32_t k1,
                                             uint32_t x0, uint32_t x1,
                                             uint32_t& o0, uint32_t& o1) {
  const uint32_t ks2 = k0 ^ k1 ^ 0x1BD11BDAu;
  x0 += k0; x1 += k1;
#define TF_R4(a, b, c, d)                                     \
  x0 += x1; x1 = rotl32(x1, a); x1 ^= x0;                     \
  x0 += x1; x1 = rotl32(x1, b); x1 ^= x0;                     \
  x0 += x1; x1 = rotl32(x1, c); x1 ^= x0;                     \
  x0 += x1; x1 = rotl32(x1, d); x1 ^= x0;
  TF_R4(13, 15, 26, 6)  x0 += k1;  x1 += ks2 + 1u;
  TF_R4(17, 29, 16, 24) x0 += ks2; x1 += k0 + 2u;
  TF_R4(13, 15, 26, 6)  x0 += k0;  x1 += k1 + 3u;
  TF_R4(17, 29, 16, 24) x0 += k1;  x1 += ks2 + 4u;
  TF_R4(13, 15, 26, 6)  x0 += ks2; x1 += k0 + 5u;
#undef TF_R4
  o0 = x0; o1 = x1;
}

__device__ __forceinline__ unsigned long long gumbel_pack(float s, uint32_t key0,
                                                          uint32_t key1, int b, int v) {
  uint32_t j = (uint32_t)(b * VOCAB + v);
  uint32_t o0, o1;
  threefry2x32(key0, key1, 0u, j, o0, o1);
  uint32_t bits = o0 ^ o1;
  float f = __uint_as_float((bits >> 9) | 0x3f800000u) - 1.0f;
  float u = fmaxf(f, 1.17549435e-38f);
  float g = -__logf(-__logf(u));
  s += g;
  uint32_t us = __float_as_uint(s);
  us = (us & 0x80000000u) ? ~us : (us | 0x80000000u);
  return ((unsigned long long)us << 32) | (uint32_t)(~(uint32_t)v);
}

// split helper: val*scale -> {fp16 hi, fp16 lo = raw residual (UNSCALED)}.
// Unscaled lo lets hi*hi + hi*lo + lo*hi accumulate into ONE accumulator.
struct hl16 { _Float16 hi, lo; };
__device__ __forceinline__ hl16 split16(float val, float scale) {
  float s = val * scale;
  _Float16 h = (_Float16)s;
  hl16 r;
  r.hi = h;
  r.lo = (_Float16)(s - (float)h);
  return r;
}

// ---------------- init ----------------
__global__ void k_init(const float* __restrict__ z, const int* __restrict__ l,
                       const float* __restrict__ attr_w, const float* __restrict__ emb_w,
                       float* __restrict__ hbuf0, uint32_t* __restrict__ keys,
                       unsigned long long* __restrict__ slots,
                       int* __restrict__ tok, float* __restrict__ y_out,
                       _Float16* __restrict__ h_hi, _Float16* __restrict__ h_lo,
                       _Float16* __restrict__ ht,
                       _Float16* __restrict__ x0_hi, _Float16* __restrict__ x0_lo,
                       _Float16* __restrict__ xe_hi, _Float16* __restrict__ xe_lo,
                       int full) {
  int idx = blockIdx.x * blockDim.x + threadIdx.x;
  if (idx < B * HID) {
    int b = idx / HID, i = idx % HID;
    float v = (i < ZDIM) ? z[b * ZDIM + i]
                         : attr_w[l[b] * ATTR_EMBD + (i - ZDIM)];
    hbuf0[idx] = v;
    hl16 r = split16(v, 8.0f);
    h_hi[b * KP + i] = r.hi;
    h_lo[b * KP + i] = r.lo;
  }
  if (idx < MAXLEN) {
    uint32_t o0, o1;
    threefry2x32(0u, 42u, 0u, (uint32_t)idx, o0, o1);
    keys[2 * idx] = o0; keys[2 * idx + 1] = o1;
  }
  if (idx < MAXLEN * B) slots[idx] = 0ull;
  if (idx < B) {
    tok[idx] = SOS_IDX;
    tok[31 * B + idx] = EOS_IDX;
    y_out[idx * SEQ + MAXLEN] = 2.0f;
  }
  if (idx < B * 4) {  // zero k-pad (700..703) of linear + tiled h (kt=21, kc=3)
    int b = idx >> 2, k = HID + (idx & 3);
    h_hi[b * KP + k] = (_Float16)0.0f;
    h_lo[b * KP + k] = (_Float16)0.0f;
    int c = b >> 7, row = b & 127, e = k & 7;
    size_t tb = (size_t)c * TILE_STRIDE + (size_t)21 * 2 * CHUNK
              + (3 * 128 + row) * 8 + e;
    ht[tb] = (_Float16)0.0f;
    ht[tb + CHUNK] = (_Float16)0.0f;
  }
  if (full && idx < KIH) {
    float v0 = (idx < EMB) ? emb_w[SOS_IDX * EMB + idx] : 0.0f;
    float ve = (idx < EMB) ? emb_w[EOS_IDX * EMB + idx] : 0.0f;
    hl16 r0 = split16(v0, 8.0f);
    hl16 re = split16(ve, 8.0f);
    for (int b = 0; b < B; ++b) {  // broadcast rows (all batches share SOS/EOS)
      x0_hi[b * KIH + idx] = r0.hi; x0_lo[b * KIH + idx] = r0.lo;
      xe_hi[b * KIH + idx] = re.hi; xe_lo[b * KIH + idx] = re.lo;
    }
  }
}

// ---------------- logits w split -> TILED fragment-image layout ----------------
__global__ void k_wsplit(const float* __restrict__ out_w, _Float16* __restrict__ wt) {
  size_t idx = (size_t)blockIdx.x * blockDim.x + threadIdx.x;
  if (idx >= (size_t)NVT * NKT * 1024) return;
  int h4 = (int)(idx & 1023);
  int ktp = (int)(idx >> 10);
  int kt = ktp % NKT, p = ktp / NKT;
  int slot4 = h4 >> 1, e0 = (h4 & 1) * 4;
  int kc = slot4 >> 7, row = slot4 & 127;
  int v = p * 128 + row;
  int k = kt * 32 + kc * 8 + e0;
  float x[4];
  if (v < VOCAB && k + 3 < HID) {
    const float4 xv = *(const float4*)&out_w[(size_t)v * HID + k];
    x[0] = xv.x; x[1] = xv.y; x[2] = xv.z; x[3] = xv.w;
  } else {
#pragma unroll
    for (int j = 0; j < 4; ++j)
      x[j] = (v < VOCAB && k + j < HID) ? out_w[(size_t)v * HID + k + j] : 0.0f;
  }
  half4 hi, lo;
#pragma unroll
  for (int j = 0; j < 4; ++j) {
    hl16 r = split16(x[j], 64.0f);
    hi[j] = r.hi; lo[j] = r.lo;
  }
  size_t base = (size_t)p * TILE_STRIDE + (size_t)kt * 2 * CHUNK + slot4 * 8 + e0;
  *(half4*)&wt[base] = hi;
  *(half4*)&wt[base + CHUNK] = lo;
}

// ---------------- generic gate-weight split (Msrc x Ksrc -> MPAD x Kpad) ----------------
__global__ void k_gwsplit(const float* __restrict__ src, _Float16* __restrict__ hi,
                          _Float16* __restrict__ lo, int Msrc, int Ksrc, int Kpad,
                          int tot4) {
  int idx = blockIdx.x * blockDim.x + threadIdx.x;
  if (idx >= tot4) return;
  size_t i4 = (size_t)idx * 4;
  int m = (int)(i4 / Kpad), k = (int)(i4 % Kpad);
  half4 h, l;
#pragma unroll
  for (int j = 0; j < 4; ++j) {
    float x = (m < Msrc && k + j < Ksrc) ? src[(size_t)m * Ksrc + k + j] : 0.0f;
    hl16 r = split16(x, 64.0f);
    h[j] = r.hi; l[j] = r.lo;
  }
  *(half4*)&hi[i4] = h;
  *(half4*)&lo[i4] = l;
}

// ---------------- MFMA gates: 64j x 64b blocks, 4 waves (32x32), merged acc ----
__global__ __launch_bounds__(256, 4)
void k_gates2(const _Float16* __restrict__ wih_hi, const _Float16* __restrict__ wih_lo,
              const _Float16* __restrict__ whh_hi, const _Float16* __restrict__ whh_lo,
              const _Float16* __restrict__ x_hi, const _Float16* __restrict__ x_lo,
              const _Float16* __restrict__ h_hi, const _Float16* __restrict__ h_lo,
              float* __restrict__ gi, float* __restrict__ gh) {
  const int zz = blockIdx.z;
  const _Float16* __restrict__ Whi = zz ? whh_hi : wih_hi;
  const _Float16* __restrict__ Wlo = zz ? whh_lo : wih_lo;
  const _Float16* __restrict__ Xhi = zz ? h_hi : x_hi;
  const _Float16* __restrict__ Xlo = zz ? h_lo : x_lo;
  const int Kz = zz ? KP : KIH;
  float* __restrict__ out = zz ? gh : gi;

  const int jbase = blockIdx.x * 64;
  const int bbase = blockIdx.y * 64;
  __shared__ float4 lds[2][4][256];   // [buf][whi,wlo,xhi,xlo][kc*64+row]
  const int tid = threadIdx.x, lane = tid & 63, wid = tid >> 6;
  const int wj = wid >> 1, wb2 = wid & 1;
  const size_t wrow = (size_t)(jbase + lane) * Kz;   // stage: kc=wid, row=lane
  const size_t xrow = (size_t)(bbase + lane) * Kz;

  f32x4 acc[2][2];
#pragma unroll
  for (int i = 0; i < 2; ++i)
#pragma unroll
    for (int j = 0; j < 2; ++j) acc[i][j] = (f32x4)0.0f;

#define GSTAGE(bf, k0)                                                   \
  {                                                                      \
    gload_lds16(Whi + wrow + (k0) + wid * 8, &lds[bf][0][wid * 64]);     \
    gload_lds16(Wlo + wrow + (k0) + wid * 8, &lds[bf][1][wid * 64]);     \
    gload_lds16(Xhi + xrow + (k0) + wid * 8, &lds[bf][2][wid * 64]);     \
    gload_lds16(Xlo + xrow + (k0) + wid * 8, &lds[bf][3][wid * 64]);     \
  }

  const int nt = Kz / 32;
  GSTAGE(0, 0)
  for (int kt = 0; kt < nt; ++kt) {
    const int cur = kt & 1;
    __syncthreads();                       // drains staged loads for buf[cur]
    if (kt + 1 < nt) GSTAGE(cur ^ 1, (kt + 1) * 32)
    const int kcf = (lane >> 4) * 64 + (lane & 15);
    half8 a_hi[2], a_lo[2];
#pragma unroll
    for (int fv = 0; fv < 2; ++fv) {
      int s = kcf + wj * 32 + fv * 16;
      a_hi[fv] = *(const half8*)&lds[cur][0][s];
      a_lo[fv] = *(const half8*)&lds[cur][1][s];
    }
#pragma unroll
    for (int fb = 0; fb < 2; ++fb) {
      int s = kcf + wb2 * 32 + fb * 16;
      half8 b_hi = *(const half8*)&lds[cur][2][s];
      half8 b_lo = *(const half8*)&lds[cur][3][s];
#pragma unroll
      for (int fv = 0; fv < 2; ++fv) {
        acc[fv][fb] = __builtin_amdgcn_mfma_f32_16x16x32_f16(a_hi[fv], b_hi,
                                                             acc[fv][fb], 0, 0, 0);
        acc[fv][fb] = __builtin_amdgcn_mfma_f32_16x16x32_f16(a_hi[fv], b_lo,
                                                             acc[fv][fb], 0, 0, 0);
        acc[fv][fb] = __builtin_amdgcn_mfma_f32_16x16x32_f16(a_lo[fv], b_hi,
                                                             acc[fv][fb], 0, 0, 0);
      }
    }
  }
#undef GSTAGE

  const float c2 = 1.0f / 512.0f;
#pragma unroll
  for (int fb = 0; fb < 2; ++fb) {
    const int b = bbase + wb2 * 32 + fb * 16 + (lane & 15);
#pragma unroll
    for (int fv = 0; fv < 2; ++fv) {
#pragma unroll
      for (int r = 0; r < 4; ++r) {
        int j = jbase + wj * 32 + fv * 16 + (lane >> 4) * 4 + r;
        if (j < G3) out[b * G3 + j] = acc[fv][fb][r] * c2;
      }
    }
  }
}

// ---------------- fp32 gates fallback ----------------
__global__ void k_gates(const float* __restrict__ W_ih, const float* __restrict__ W_hh,
                        const float* __restrict__ emb_w, const float* __restrict__ hprev,
                        const int* __restrict__ tok,
                        float* __restrict__ gi, float* __restrict__ gh) {
  const int zz = blockIdx.z;
  const float* __restrict__ W = zz ? W_hh : W_ih;
  const int K = zz ? HID : EMB;
  float* __restrict__ out = zz ? gh : gi;
  __shared__ float w_lds[20][36];
  __shared__ float xh_lds[20][36];
  const int jbase = blockIdx.x * 32;
  const int bbase = blockIdx.y * 32;
  const int tid = threadIdx.x;
  const int tj = tid % 16, tb = tid / 16;
  float a00 = 0.f, a01 = 0.f, a10 = 0.f, a11 = 0.f;
  for (int k0 = 0; k0 < K; k0 += 20) {
    for (int idx = tid; idx < 640; idx += 256) {
      int col = idx / 20, kk = idx % 20;
      int j = jbase + col;
      w_lds[kk][col] = (j < G3) ? W[j * K + k0 + kk] : 0.0f;
      int b = bbase + col;
      float xv;
      if (zz) xv = hprev[b * HID + k0 + kk];
      else    xv = emb_w[tok[b] * EMB + k0 + kk];
      xh_lds[kk][col] = xv;
    }
    __syncthreads();
#pragma unroll
    for (int kk = 0; kk < 20; ++kk) {
      float w0 = w_lds[kk][tj * 2], w1 = w_lds[kk][tj * 2 + 1];
      float h0 = xh_lds[kk][tb * 2], h1 = xh_lds[kk][tb * 2 + 1];
      a00 += w0 * h0; a01 += w0 * h1;
      a10 += w1 * h0; a11 += w1 * h1;
    }
    __syncthreads();
  }
  int j0 = jbase + tj * 2, b0 = bbase + tb * 2;
  if (j0 < G3)     { out[b0 * G3 + j0] = a00;     out[(b0 + 1) * G3 + j0] = a01; }
  if (j0 + 1 < G3) { out[b0 * G3 + j0 + 1] = a10; out[(b0 + 1) * G3 + j0 + 1] = a11; }
}

// ---------------- pointwise GRU update + h fp16-split (linear for gates, tiled for logits)
__global__ void k_hnew(const float* __restrict__ gi, const float* __restrict__ gh,
                       const float* __restrict__ b_ih, const float* __restrict__ b_hh,
                       const float* __restrict__ hprev, float* __restrict__ hnext,
                       float* __restrict__ hy, _Float16* __restrict__ h_hi,
                       _Float16* __restrict__ h_lo, _Float16* __restrict__ ht, int t) {
  int idx = blockIdx.x * blockDim.x + threadIdx.x;
  if (idx >= B * HID) return;
  int b = idx / HID, i = idx % HID;
  float ir = gi[b * G3 + i]            + b_ih[i];
  float iz = gi[b * G3 + HID + i]      + b_ih[HID + i];
  float in_ = gi[b * G3 + 2 * HID + i] + b_ih[2 * HID + i];
  float hr = gh[b * G3 + i]            + b_hh[i];
  float hz = gh[b * G3 + HID + i]      + b_hh[HID + i];
  float hn = gh[b * G3 + 2 * HID + i]  + b_hh[2 * HID + i];
  float r  = 1.0f / (1.0f + expf(-(ir + hr)));
  float zg = 1.0f / (1.0f + expf(-(iz + hz)));
  float n  = tanhf(in_ + r * hn);
  float h  = (1.0f - zg) * n + zg * hprev[idx];
  hnext[idx] = h;
  hy[(size_t)b * SEQ * HID + (size_t)t * HID + i] = h;
  hl16 rr = split16(h, 8.0f);
  h_hi[b * KP + i] = rr.hi;
  h_lo[b * KP + i] = rr.lo;
  // tiled image for k_logits7: c=b>>7 (128-row halves), row=b&127,
  // kt=i>>5, kc=(i>>3)&3, e=i&7
  int c = b >> 7, row = b & 127;
  size_t tb = (size_t)c * TILE_STRIDE + (size_t)(i >> 5) * 2 * CHUNK
            + ((((i >> 3) & 3) * 128 + row) * 8) + (i & 7);
  ht[tb] = rr.hi;
  ht[tb + CHUNK] = rr.lo;
}

// ---------------- MFMA logits v8: counted-vmcnt pipeline (T3+T4+T5) ----
// r9 structure (h LDS-staged, w regs) upgraded: 3-buffer LDS h + raw s_barrier
// + counted `s_waitcnt vmcnt(4)` (never full-drain in the loop; stage-to-
// consume distance 2), w regs 3-deep at distance 2 (static names W0/W1/W2,
// rule #20), setprio around the MFMA cluster. vmcnt(4) is safe under ANY
// placement of the plain w-loads: VMEM retires in order and SH(kt) always has
// >= 4 younger ops (SH(kt+1)), so outstanding<=4 implies SH(kt) complete.
__global__ __launch_bounds__(256, 3)
void k_logits7(const _Float16* __restrict__ wt, const _Float16* __restrict__ ht,
               const float* __restrict__ out_b, const uint32_t* __restrict__ keys,
               unsigned long long* __restrict__ slot, int t) {
  const int item = (blockIdx.x & 7) * 197 + (blockIdx.x >> 3);  // XCD-chunked
  if (item >= NIT5) return;
  const int p = item >> 2, vh = (item >> 1) & 1, c = item & 1;

  __shared__ float4 ldsh[3][1024];   // [buf][part*512 + kc*128 + row]
  const int tid = threadIdx.x, lane = tid & 63, wid = tid >> 6;
  const int wv = wid >> 1, wb = wid & 1;
  const int lq = lane >> 4, lr = lane & 15;

  const _Float16* __restrict__ wp = wt + (size_t)p * TILE_STRIDE;
  const _Float16* __restrict__ hp = ht + (size_t)c * TILE_STRIDE;

  const int wslot = lq * 128 + vh * 64 + wv * 32 + lr;   // + fv*16
  const int hslot = lq * 128 + wb * 64 + lr;             // + fb*16 (+part*512)

  f32x4 acc[2][4];
#pragma unroll
  for (int i = 0; i < 2; ++i)
#pragma unroll
    for (int j = 0; j < 4; ++j) acc[i][j] = (f32x4)0.0f;

  half8 W0[4], W1[4], W2[4];   // [fv*2 + part]; rotating 3-deep (distance 2)

#define LOADW(W, ktv)                                                         \
  {                                                                           \
    const _Float16* bw = wp + (size_t)(ktv) * (2 * CHUNK);                    \
    _Pragma("unroll")                                                         \
    for (int fv = 0; fv < 2; ++fv) {                                          \
      W[fv * 2 + 0] = *(const half8*)(bw + (wslot + fv * 16) * 8);            \
      W[fv * 2 + 1] = *(const half8*)(bw + CHUNK + (wslot + fv * 16) * 8);    \
    }                                                                         \
  }
#define STAGEH(bf, ktv)                                                       \
  {                                                                           \
    const _Float16* bh = hp + (size_t)(ktv) * (2 * CHUNK);                    \
    _Pragma("unroll")                                                         \
    for (int j = 0; j < 4; ++j)                                               \
      gload_lds16(bh + (j * 256 + wid * 64 + lane) * 8,                       \
                  &ldsh[bf][j * 256 + wid * 64]);                             \
  }
#define MFMAB(W, BF)                                                          \
  _Pragma("unroll")                                                           \
  for (int fb = 0; fb < 4; ++fb) {                                            \
    half8 hhi = *(const half8*)&ldsh[BF][hslot + fb * 16];                    \
    half8 hlo = *(const half8*)&ldsh[BF][512 + hslot + fb * 16];              \
    _Pragma("unroll")                                                         \
    for (int fv = 0; fv < 2; ++fv) {                                          \
      acc[fv][fb] = __builtin_amdgcn_mfma_f32_16x16x32_f16(                   \
          W[fv * 2 + 0], hhi, acc[fv][fb], 0, 0, 0);                          \
      acc[fv][fb] = __builtin_amdgcn_mfma_f32_16x16x32_f16(                   \
          W[fv * 2 + 0], hlo, acc[fv][fb], 0, 0, 0);                          \
      acc[fv][fb] = __builtin_amdgcn_mfma_f32_16x16x32_f16(                   \
          W[fv * 2 + 1], hhi, acc[fv][fb], 0, 0, 0);                          \
    }                                                                         \
  }
// STEP(kt): wait own SH(kt) done (counted, not 0) -> barrier -> stage kt+2
// into buf[(kt+2)%3] (safe: last read iter kt-1, before this barrier) ->
// load w(kt+2) -> MFMA on buf[kt%3] with W(kt%3).
#define STEP(ktv, BC, BP, WCUR, WNEW)                                         \
  {                                                                           \
    asm volatile("s_waitcnt vmcnt(4)" ::: "memory");                          \
    __builtin_amdgcn_sched_barrier(0);                                        \
    __builtin_amdgcn_s_barrier();                                             \
    __builtin_amdgcn_sched_barrier(0);                                        \
    if ((ktv) + 2 < NKT) {                                                    \
      STAGEH(BP, (ktv) + 2)                                                   \
      LOADW(WNEW, (ktv) + 2)                                                  \
    }                                                                         \
    __builtin_amdgcn_s_setprio(1);                                            \
    MFMAB(WCUR, BC)                                                           \
    __builtin_amdgcn_s_setprio(0);                                            \
  }

  STAGEH(0, 0)
  STAGEH(1, 1)
  LOADW(W0, 0)
  LOADW(W1, 1)
#pragma unroll 1
  for (int base = 0; base < 21; base += 3) {
    STEP(base + 0, 0, 2, W0, W2)
    STEP(base + 1, 1, 0, W1, W0)
    STEP(base + 2, 2, 1, W2, W1)
  }
  STEP(21, 0, 2, W0, W2)   // 21%3==0; stage predicate false
#undef STEP
#undef LOADW
#undef STAGEH
#undef MFMAB

  const uint32_t key0 = keys[2 * t], key1 = keys[2 * t + 1];
  const float c2 = 1.0f / 512.0f;
  const int vbase0 = p * 128 + vh * 64 + wv * 32;
#pragma unroll
  for (int fb = 0; fb < 4; ++fb) {
    const int b = c * 128 + wb * 64 + fb * 16 + lr;
    unsigned long long best = 0ull;
#pragma unroll
    for (int fv = 0; fv < 2; ++fv) {
#pragma unroll
      for (int r = 0; r < 4; ++r) {
        int v = vbase0 + fv * 16 + lq * 4 + r;
        if (v < VOCAB) {
          float s = acc[fv][fb][r] * c2 + out_b[v];
          unsigned long long cand = gumbel_pack(s, key0, key1, b, v);
          if (cand > best) best = cand;
        }
      }
    }
    unsigned long long o;
    o = __shfl_xor(best, 16, 64); if (o > best) best = o;
    o = __shfl_xor(best, 32, 64); if (o > best) best = o;
    if (lq == 0) atomicMax(&slot[b], best);
  }
}

// ---------------- fp32 logits fallback ----------------
#define WPITCH 68
#define HPITCH 260
__global__ __launch_bounds__(256)
void k_logits_f32(const float* __restrict__ h, const float* __restrict__ out_w,
                  const float* __restrict__ out_b, const uint32_t* __restrict__ keys,
                  unsigned long long* __restrict__ slot, int t) {
  __shared__ float w_lds[20][WPITCH];
  __shared__ float h_lds[20][HPITCH];
  const int vbase = blockIdx.x * 64;
  const int tid = threadIdx.x;
  const int tv = tid % 8, tb = tid / 8;
  float acc[8][8];
#pragma unroll
  for (int i = 0; i < 8; ++i)
#pragma unroll
    for (int j = 0; j < 8; ++j) acc[i][j] = 0.f;

  for (int k0 = 0; k0 < HID; k0 += 20) {
    for (int idx = tid; idx < 64 * 20; idx += 256) {
      int vv = idx / 20, kk = idx % 20;
      int v = vbase + vv;
      w_lds[kk][vv] = (v < VOCAB) ? out_w[(size_t)v * HID + k0 + kk] : 0.0f;
    }
    for (int idx = tid; idx < 256 * 20; idx += 256) {
      int bb = idx / 20, kk = idx % 20;
      h_lds[kk][bb] = h[bb * HID + k0 + kk];
    }
    __syncthreads();
#pragma unroll
    for (int kk = 0; kk < 20; ++kk) {
      float wv[8], hv[8];
      *(float4*)&wv[0] = *(const float4*)&w_lds[kk][tv * 8];
      *(float4*)&wv[4] = *(const float4*)&w_lds[kk][tv * 8 + 4];
      *(float4*)&hv[0] = *(const float4*)&h_lds[kk][tb * 8];
      *(float4*)&hv[4] = *(const float4*)&h_lds[kk][tb * 8 + 4];
#pragma unroll
      for (int iv = 0; iv < 8; ++iv)
#pragma unroll
        for (int ib = 0; ib < 8; ++ib) acc[iv][ib] += wv[iv] * hv[ib];
    }
    __syncthreads();
  }

  const uint32_t key0 = keys[2 * t], key1 = keys[2 * t + 1];
#pragma unroll
  for (int ib = 0; ib < 8; ++ib) {
    const int b = tb * 8 + ib;
    unsigned long long best = 0ull;
#pragma unroll
    for (int iv = 0; iv < 8; ++iv) {
      int v = vbase + tv * 8 + iv;
      if (v >= VOCAB) continue;
      unsigned long long cand = gumbel_pack(acc[iv][ib] + out_b[v], key0, key1, b, v);
      if (cand > best) best = cand;
    }
#pragma unroll
    for (int off = 1; off < 8; off <<= 1) {
      unsigned long long other = __shfl_xor(best, off, 64);
      if (other > best) best = other;
    }
    if (tv == 0) atomicMax(&slot[b], best);
  }
}

// ---------------- token extraction + emb gather/split ----------------
__global__ void k_tok2(const unsigned long long* __restrict__ slot,
                       const float* __restrict__ emb_w,
                       int* __restrict__ tok_next, float* __restrict__ y_out,
                       _Float16* __restrict__ xc_hi, _Float16* __restrict__ xc_lo,
                       int t, int full) {
  const int b = blockIdx.x;
  const int c = threadIdx.x;   // 128 threads
  unsigned long long p = slot[b];
  uint32_t v = ~((uint32_t)(p & 0xFFFFFFFFull));
  if (c == 0) {
    tok_next[b] = (int)v;
    y_out[b * SEQ + t] = (float)v;
  }
  if (!full) return;
  if (c < 75) {
    float4 xv = *(const float4*)&emb_w[(size_t)v * EMB + c * 4];
    half4 hi, lo;
    hl16 r0 = split16(xv.x, 8.0f); hi[0] = r0.hi; lo[0] = r0.lo;
    hl16 r1 = split16(xv.y, 8.0f); hi[1] = r1.hi; lo[1] = r1.lo;
    hl16 r2 = split16(xv.z, 8.0f); hi[2] = r2.hi; lo[2] = r2.lo;
    hl16 r3 = split16(xv.w, 8.0f); hi[3] = r3.hi; lo[3] = r3.lo;
    *(half4*)&xc_hi[b * KIH + c * 4] = hi;
    *(half4*)&xc_lo[b * KIH + c * 4] = lo;
  } else if (c < 80) {
    *(half4*)&xc_hi[b * KIH + c * 4] = (half4)(_Float16)0.0f;
    *(half4*)&xc_lo[b * KIH + c * 4] = (half4)(_Float16)0.0f;
  }
}

// ---------------- host launch ----------------
extern "C" void kernel_launch(void* const* d_in, const int* in_sizes, int n_in,
                              void* d_out, int out_size, void* d_ws, size_t ws_size,
                              hipStream_t stream) {
  const float* z      = (const float*)d_in[0];
  const int*   l      = (const int*)  d_in[1];
  const float* emb_w  = (const float*)d_in[2];
  const float* attr_w = (const float*)d_in[3];
  const float* W_ih   = (const float*)d_in[4];
  const float* W_hh   = (const float*)d_in[5];
  const float* b_ih   = (const float*)d_in[6];
  const float* b_hh   = (const float*)d_in[7];
  const float* out_w  = (const float*)d_in[8];
  const float* out_b  = (const float*)d_in[9];

  float* hy    = (float*)d_out;
  float* y_out = (float*)d_out + HY_ELEMS;

  char* ws = (char*)d_ws;
  size_t off = 0;
  uint32_t* keys            = (uint32_t*)(ws + off);           off += 256;
  unsigned long long* slots = (unsigned long long*)(ws + off); off += (size_t)MAXLEN * B * 8;
  int* tokbuf               = (int*)(ws + off);                off += (size_t)32 * B * 4;
  float* hbuf               = (float*)(ws + off);              off += (size_t)2 * B * HID * 4;
  float* gi                 = (float*)(ws + off);              off += (size_t)B * G3 * 4;
  float* gh                 = (float*)(ws + off);              off += (size_t)B * G3 * 4;
  _Float16* h_hi            = (_Float16*)(ws + off);           off += (size_t)B * KP * 2;
  _Float16* h_lo            = (_Float16*)(ws + off);           off += (size_t)B * KP * 2;
  _Float16* ht              = (_Float16*)(ws + off);           off += (size_t)2 * TILE_STRIDE * 2;
  _Float16* wt              = (_Float16*)(ws + off);           off += (size_t)NVT * TILE_STRIDE * 2;
  const size_t tier1_end = off;
  _Float16* wih_hi          = (_Float16*)(ws + off);           off += (size_t)MPAD * KIH * 2;
  _Float16* wih_lo          = (_Float16*)(ws + off);           off += (size_t)MPAD * KIH * 2;
  _Float16* whh_hi          = (_Float16*)(ws + off);           off += (size_t)MPAD * KP * 2;
  _Float16* whh_lo          = (_Float16*)(ws + off);           off += (size_t)MPAD * KP * 2;
  _Float16* x0_hi           = (_Float16*)(ws + off);           off += (size_t)B * KIH * 2;
  _Float16* x0_lo           = (_Float16*)(ws + off);           off += (size_t)B * KIH * 2;
  _Float16* xe_hi           = (_Float16*)(ws + off);           off += (size_t)B * KIH * 2;
  _Float16* xe_lo           = (_Float16*)(ws + off);           off += (size_t)B * KIH * 2;
  _Float16* xc_hi           = (_Float16*)(ws + off);           off += (size_t)B * KIH * 2;
  _Float16* xc_lo           = (_Float16*)(ws + off);           off += (size_t)B * KIH * 2;
  const size_t tier2_end = off;
  const int tier = (ws_size >= tier2_end) ? 2 : ((ws_size >= tier1_end) ? 1 : 0);

  k_init<<<(B * HID + 255) / 256, 256, 0, stream>>>(
      z, l, attr_w, emb_w, hbuf, keys, slots, tokbuf, y_out, h_hi, h_lo, ht,
      x0_hi, x0_lo, xe_hi, xe_lo, (tier == 2) ? 1 : 0);

  if (tier >= 1) {
    size_t tot = (size_t)NVT * NKT * 1024;
    k_wsplit<<<(int)((tot + 255) / 256), 256, 0, stream>>>(out_w, wt);
  }
  if (tier == 2) {
    int tih = MPAD * KIH / 4, thh = MPAD * KP / 4;
    k_gwsplit<<<(tih + 255) / 256, 256, 0, stream>>>(W_ih, wih_hi, wih_lo, G3, EMB, KIH, tih);
    k_gwsplit<<<(thh + 255) / 256, 256, 0, stream>>>(W_hh, whh_hi, whh_lo, G3, HID, KP, thh);
  }

  for (int t = 0; t <= MAXLEN; ++t) {
    float* hprev = hbuf + (t % 2) * B * HID;
    float* hnext = hbuf + ((t + 1) % 2) * B * HID;

    if (tier == 2) {
      const _Float16* xh = (t == 0) ? x0_hi : ((t == MAXLEN) ? xe_hi : xc_hi);
      const _Float16* xl = (t == 0) ? x0_lo : ((t == MAXLEN) ? xe_lo : xc_lo);
      dim3 g2(33, 4, 2);
      k_gates2<<<g2, 256, 0, stream>>>(wih_hi, wih_lo, whh_hi, whh_lo,
                                       xh, xl, h_hi, h_lo, gi, gh);
    } else {
      const int* tok_t = tokbuf + ((t == MAXLEN) ? 31 : t) * B;
      dim3 ggrid(66, 8, 2);
      k_gates<<<ggrid, 256, 0, stream>>>(W_ih, W_hh, emb_w, hprev, tok_t, gi, gh);
    }
    k_hnew<<<(B * HID + 255) / 256, 256, 0, stream>>>(gi, gh, b_ih, b_hh, hprev,
                                                      hnext, hy, h_hi, h_lo, ht, t);
    if (t < MAXLEN) {
      if (tier >= 1) {
        k_logits7<<<NBLK5, 256, 0, stream>>>(wt, ht, out_b, keys,
                                             slots + (size_t)t * B, t);
      } else {
        k_logits_f32<<<(VOCAB + 63) / 64, 256, 0, stream>>>(hnext, out_w, out_b, keys,
                                                            slots + (size_t)t * B, t);
      }
      k_tok2<<<B, 128, 0, stream>>>(slots + (size_t)t * B, emb_w,
                                    tokbuf + (t + 1) * B, y_out, xc_hi, xc_lo,
                                    t, (tier == 2) ? 1 : 0);
    }
  }
}

// Round 12
// 3622.513 us; speedup vs baseline: 1.0573x; 1.0322x over previous
//
#include <hip/hip_runtime.h>
#include <stdint.h>

#define VOCAB 50257
#define B 256
#define EMB 300
#define HID 700
#define G3 2100          // 3*HID
#define ZDIM 500
#define ATTR_EMBD 200
#define MAXLEN 30
#define SEQ 31           // MAXLEN+1
#define HY_ELEMS (B*SEQ*HID)
#define KP 704           // HID padded to mult of 32
#define NKT 22           // KP/32 k-tiles
#define KIH 320          // EMB padded to mult of 32
#define VPAD 50304       // VOCAB padded to mult of 128 (393*128)
#define NVT 393          // VPAD/128
#define MPAD 2112        // G3 padded to 33*64
#define SOS_IDX 1
#define EOS_IDX 2
// tiled chunk: per (tile, kt): [part(2)][4096 halves]; half idx = (kc*128+row)*8+e
#define CHUNK 4096
#define TILE_STRIDE ((size_t)NKT * 2 * CHUNK)   // halves per v-panel / h half-tile
// logits grid: items = (panel, v-half, b-half) = 393*2*2 = 1572; 8 XCD x 197
#define NIT5 1572
#define NBLK5 1576

typedef _Float16 half8 __attribute__((ext_vector_type(8)));
typedef _Float16 half4 __attribute__((ext_vector_type(4)));
typedef float f32x4 __attribute__((ext_vector_type(4)));

// ---------------- global_load_lds helper (16B per lane, dest = wave base + lane*16)
typedef const __attribute__((address_space(1))) void* gas1_t;
typedef __attribute__((address_space(3))) void* las3_t;
__device__ __forceinline__ void gload_lds16(const void* g, void* l) {
  __builtin_amdgcn_global_load_lds((gas1_t)g, (las3_t)l, 16, 0, 0);
}

// ---------------- threefry2x32 (JAX-exact, 20 rounds) ----------------
__device__ __forceinline__ uint32_t rotl32(uint32_t x, int r) {
  return (x << r) | (x >> (32 - r));
}

__device__ __forceinline__ void threefry2x32(uint32_t k0, uint32_t k1,
                                             uint32_t x0, uint32_t x1,
                                             uint32_t& o0, uint32_t& o1) {
  const uint32_t ks2 = k0 ^ k1 ^ 0x1BD11BDAu;
  x0 += k0; x1 += k1;
#define TF_R4(a, b, c, d)                                     \
  x0 += x1; x1 = rotl32(x1, a); x1 ^= x0;                     \
  x0 += x1; x1 = rotl32(x1, b); x1 ^= x0;                     \
  x0 += x1; x1 = rotl32(x1, c); x1 ^= x0;                     \
  x0 += x1; x1 = rotl32(x1, d); x1 ^= x0;
  TF_R4(13, 15, 26, 6)  x0 += k1;  x1 += ks2 + 1u;
  TF_R4(17, 29, 16, 24) x0 += ks2; x1 += k0 + 2u;
  TF_R4(13, 15, 26, 6)  x0 += k0;  x1 += k1 + 3u;
  TF_R4(17, 29, 16, 24) x0 += k1;  x1 += ks2 + 4u;
  TF_R4(13, 15, 26, 6)  x0 += ks2; x1 += k0 + 5u;
#undef TF_R4
  o0 = x0; o1 = x1;
}

__device__ __forceinline__ unsigned long long gumbel_pack(float s, uint32_t key0,
                                                          uint32_t key1, int b, int v) {
  uint32_t j = (uint32_t)(b * VOCAB + v);
  uint32_t o0, o1;
  threefry2x32(key0, key1, 0u, j, o0, o1);
  uint32_t bits = o0 ^ o1;
  float f = __uint_as_float((bits >> 9) | 0x3f800000u) - 1.0f;
  float u = fmaxf(f, 1.17549435e-38f);
  float g = -__logf(-__logf(u));
  s += g;
  uint32_t us = __float_as_uint(s);
  us = (us & 0x80000000u) ? ~us : (us | 0x80000000u);
  return ((unsigned long long)us << 32) | (uint32_t)(~(uint32_t)v);
}

// split helper: val*scale -> {fp16 hi, fp16 lo = raw residual (UNSCALED)}.
struct hl16 { _Float16 hi, lo; };
__device__ __forceinline__ hl16 split16(float val, float scale) {
  float s = val * scale;
  _Float16 h = (_Float16)s;
  hl16 r;
  r.hi = h;
  r.lo = (_Float16)(s - (float)h);
  return r;
}

// ---------------- init ----------------
__global__ void k_init(const float* __restrict__ z, const int* __restrict__ l,
                       const float* __restrict__ attr_w, const float* __restrict__ emb_w,
                       float* __restrict__ hbuf0, uint32_t* __restrict__ keys,
                       unsigned long long* __restrict__ slots,
                       int* __restrict__ tok, float* __restrict__ y_out,
                       _Float16* __restrict__ h_hi, _Float16* __restrict__ h_lo,
                       _Float16* __restrict__ ht,
                       _Float16* __restrict__ x0_hi, _Float16* __restrict__ x0_lo,
                       _Float16* __restrict__ xe_hi, _Float16* __restrict__ xe_lo,
                       int full) {
  int idx = blockIdx.x * blockDim.x + threadIdx.x;
  if (idx < B * HID) {
    int b = idx / HID, i = idx % HID;
    float v = (i < ZDIM) ? z[b * ZDIM + i]
                         : attr_w[l[b] * ATTR_EMBD + (i - ZDIM)];
    hbuf0[idx] = v;
    hl16 r = split16(v, 8.0f);
    h_hi[b * KP + i] = r.hi;
    h_lo[b * KP + i] = r.lo;
  }
  if (idx < MAXLEN) {
    uint32_t o0, o1;
    threefry2x32(0u, 42u, 0u, (uint32_t)idx, o0, o1);
    keys[2 * idx] = o0; keys[2 * idx + 1] = o1;
  }
  if (idx < MAXLEN * B) slots[idx] = 0ull;
  if (idx < B) {
    tok[idx] = SOS_IDX;
    tok[31 * B + idx] = EOS_IDX;
    y_out[idx * SEQ + MAXLEN] = 2.0f;
  }
  if (idx < B * 4) {  // zero k-pad (700..703) of linear + tiled h (kt=21, kc=3)
    int b = idx >> 2, k = HID + (idx & 3);
    h_hi[b * KP + k] = (_Float16)0.0f;
    h_lo[b * KP + k] = (_Float16)0.0f;
    int c = b >> 7, row = b & 127, e = k & 7;
    size_t tb = (size_t)c * TILE_STRIDE + (size_t)21 * 2 * CHUNK
              + (3 * 128 + row) * 8 + e;
    ht[tb] = (_Float16)0.0f;
    ht[tb + CHUNK] = (_Float16)0.0f;
  }
  if (full && idx < KIH) {
    float v0 = (idx < EMB) ? emb_w[SOS_IDX * EMB + idx] : 0.0f;
    float ve = (idx < EMB) ? emb_w[EOS_IDX * EMB + idx] : 0.0f;
    hl16 r0 = split16(v0, 8.0f);
    hl16 re = split16(ve, 8.0f);
    for (int b = 0; b < B; ++b) {  // broadcast rows (all batches share SOS/EOS)
      x0_hi[b * KIH + idx] = r0.hi; x0_lo[b * KIH + idx] = r0.lo;
      xe_hi[b * KIH + idx] = re.hi; xe_lo[b * KIH + idx] = re.lo;
    }
  }
}

// ---------------- logits w split -> TILED fragment-image layout ----------------
__global__ void k_wsplit(const float* __restrict__ out_w, _Float16* __restrict__ wt) {
  size_t idx = (size_t)blockIdx.x * blockDim.x + threadIdx.x;
  if (idx >= (size_t)NVT * NKT * 1024) return;
  int h4 = (int)(idx & 1023);
  int ktp = (int)(idx >> 10);
  int kt = ktp % NKT, p = ktp / NKT;
  int slot4 = h4 >> 1, e0 = (h4 & 1) * 4;
  int kc = slot4 >> 7, row = slot4 & 127;
  int v = p * 128 + row;
  int k = kt * 32 + kc * 8 + e0;
  float x[4];
  if (v < VOCAB && k + 3 < HID) {
    const float4 xv = *(const float4*)&out_w[(size_t)v * HID + k];
    x[0] = xv.x; x[1] = xv.y; x[2] = xv.z; x[3] = xv.w;
  } else {
#pragma unroll
    for (int j = 0; j < 4; ++j)
      x[j] = (v < VOCAB && k + j < HID) ? out_w[(size_t)v * HID + k + j] : 0.0f;
  }
  half4 hi, lo;
#pragma unroll
  for (int j = 0; j < 4; ++j) {
    hl16 r = split16(x[j], 64.0f);
    hi[j] = r.hi; lo[j] = r.lo;
  }
  size_t base = (size_t)p * TILE_STRIDE + (size_t)kt * 2 * CHUNK + slot4 * 8 + e0;
  *(half4*)&wt[base] = hi;
  *(half4*)&wt[base + CHUNK] = lo;
}

// ---------------- generic gate-weight split (Msrc x Ksrc -> MPAD x Kpad) ----------------
__global__ void k_gwsplit(const float* __restrict__ src, _Float16* __restrict__ hi,
                          _Float16* __restrict__ lo, int Msrc, int Ksrc, int Kpad,
                          int tot4) {
  int idx = blockIdx.x * blockDim.x + threadIdx.x;
  if (idx >= tot4) return;
  size_t i4 = (size_t)idx * 4;
  int m = (int)(i4 / Kpad), k = (int)(i4 % Kpad);
  half4 h, l;
#pragma unroll
  for (int j = 0; j < 4; ++j) {
    float x = (m < Msrc && k + j < Ksrc) ? src[(size_t)m * Ksrc + k + j] : 0.0f;
    hl16 r = split16(x, 64.0f);
    h[j] = r.hi; l[j] = r.lo;
  }
  *(half4*)&hi[i4] = h;
  *(half4*)&lo[i4] = l;
}

// ---------------- MFMA gates: 64j x 64b blocks, 4 waves (32x32), merged acc ----
__global__ __launch_bounds__(256, 4)
void k_gates2(const _Float16* __restrict__ wih_hi, const _Float16* __restrict__ wih_lo,
              const _Float16* __restrict__ whh_hi, const _Float16* __restrict__ whh_lo,
              const _Float16* __restrict__ x_hi, const _Float16* __restrict__ x_lo,
              const _Float16* __restrict__ h_hi, const _Float16* __restrict__ h_lo,
              float* __restrict__ gi, float* __restrict__ gh) {
  const int zz = blockIdx.z;
  const _Float16* __restrict__ Whi = zz ? whh_hi : wih_hi;
  const _Float16* __restrict__ Wlo = zz ? whh_lo : wih_lo;
  const _Float16* __restrict__ Xhi = zz ? h_hi : x_hi;
  const _Float16* __restrict__ Xlo = zz ? h_lo : x_lo;
  const int Kz = zz ? KP : KIH;
  float* __restrict__ out = zz ? gh : gi;

  const int jbase = blockIdx.x * 64;
  const int bbase = blockIdx.y * 64;
  __shared__ float4 lds[2][4][256];   // [buf][whi,wlo,xhi,xlo][kc*64+row]
  const int tid = threadIdx.x, lane = tid & 63, wid = tid >> 6;
  const int wj = wid >> 1, wb2 = wid & 1;
  const size_t wrow = (size_t)(jbase + lane) * Kz;   // stage: kc=wid, row=lane
  const size_t xrow = (size_t)(bbase + lane) * Kz;

  f32x4 acc[2][2];
#pragma unroll
  for (int i = 0; i < 2; ++i)
#pragma unroll
    for (int j = 0; j < 2; ++j) acc[i][j] = (f32x4)0.0f;

#define GSTAGE(bf, k0)                                                   \
  {                                                                      \
    gload_lds16(Whi + wrow + (k0) + wid * 8, &lds[bf][0][wid * 64]);     \
    gload_lds16(Wlo + wrow + (k0) + wid * 8, &lds[bf][1][wid * 64]);     \
    gload_lds16(Xhi + xrow + (k0) + wid * 8, &lds[bf][2][wid * 64]);     \
    gload_lds16(Xlo + xrow + (k0) + wid * 8, &lds[bf][3][wid * 64]);     \
  }

  const int nt = Kz / 32;
  GSTAGE(0, 0)
  for (int kt = 0; kt < nt; ++kt) {
    const int cur = kt & 1;
    __syncthreads();                       // drains staged loads for buf[cur]
    if (kt + 1 < nt) GSTAGE(cur ^ 1, (kt + 1) * 32)
    const int kcf = (lane >> 4) * 64 + (lane & 15);
    half8 a_hi[2], a_lo[2];
#pragma unroll
    for (int fv = 0; fv < 2; ++fv) {
      int s = kcf + wj * 32 + fv * 16;
      a_hi[fv] = *(const half8*)&lds[cur][0][s];
      a_lo[fv] = *(const half8*)&lds[cur][1][s];
    }
#pragma unroll
    for (int fb = 0; fb < 2; ++fb) {
      int s = kcf + wb2 * 32 + fb * 16;
      half8 b_hi = *(const half8*)&lds[cur][2][s];
      half8 b_lo = *(const half8*)&lds[cur][3][s];
#pragma unroll
      for (int fv = 0; fv < 2; ++fv) {
        acc[fv][fb] = __builtin_amdgcn_mfma_f32_16x16x32_f16(a_hi[fv], b_hi,
                                                             acc[fv][fb], 0, 0, 0);
        acc[fv][fb] = __builtin_amdgcn_mfma_f32_16x16x32_f16(a_hi[fv], b_lo,
                                                             acc[fv][fb], 0, 0, 0);
        acc[fv][fb] = __builtin_amdgcn_mfma_f32_16x16x32_f16(a_lo[fv], b_hi,
                                                             acc[fv][fb], 0, 0, 0);
      }
    }
  }
#undef GSTAGE

  const float c2 = 1.0f / 512.0f;
#pragma unroll
  for (int fb = 0; fb < 2; ++fb) {
    const int b = bbase + wb2 * 32 + fb * 16 + (lane & 15);
#pragma unroll
    for (int fv = 0; fv < 2; ++fv) {
#pragma unroll
      for (int r = 0; r < 4; ++r) {
        int j = jbase + wj * 32 + fv * 16 + (lane >> 4) * 4 + r;
        if (j < G3) out[b * G3 + j] = acc[fv][fb][r] * c2;
      }
    }
  }
}

// ---------------- fp32 gates fallback ----------------
__global__ void k_gates(const float* __restrict__ W_ih, const float* __restrict__ W_hh,
                        const float* __restrict__ emb_w, const float* __restrict__ hprev,
                        const int* __restrict__ tok,
                        float* __restrict__ gi, float* __restrict__ gh) {
  const int zz = blockIdx.z;
  const float* __restrict__ W = zz ? W_hh : W_ih;
  const int K = zz ? HID : EMB;
  float* __restrict__ out = zz ? gh : gi;
  __shared__ float w_lds[20][36];
  __shared__ float xh_lds[20][36];
  const int jbase = blockIdx.x * 32;
  const int bbase = blockIdx.y * 32;
  const int tid = threadIdx.x;
  const int tj = tid % 16, tb = tid / 16;
  float a00 = 0.f, a01 = 0.f, a10 = 0.f, a11 = 0.f;
  for (int k0 = 0; k0 < K; k0 += 20) {
    for (int idx = tid; idx < 640; idx += 256) {
      int col = idx / 20, kk = idx % 20;
      int j = jbase + col;
      w_lds[kk][col] = (j < G3) ? W[j * K + k0 + kk] : 0.0f;
      int b = bbase + col;
      float xv;
      if (zz) xv = hprev[b * HID + k0 + kk];
      else    xv = emb_w[tok[b] * EMB + k0 + kk];
      xh_lds[kk][col] = xv;
    }
    __syncthreads();
#pragma unroll
    for (int kk = 0; kk < 20; ++kk) {
      float w0 = w_lds[kk][tj * 2], w1 = w_lds[kk][tj * 2 + 1];
      float h0 = xh_lds[kk][tb * 2], h1 = xh_lds[kk][tb * 2 + 1];
      a00 += w0 * h0; a01 += w0 * h1;
      a10 += w1 * h0; a11 += w1 * h1;
    }
    __syncthreads();
  }
  int j0 = jbase + tj * 2, b0 = bbase + tb * 2;
  if (j0 < G3)     { out[b0 * G3 + j0] = a00;     out[(b0 + 1) * G3 + j0] = a01; }
  if (j0 + 1 < G3) { out[b0 * G3 + j0 + 1] = a10; out[(b0 + 1) * G3 + j0 + 1] = a11; }
}

// ---------------- pointwise GRU update + h fp16-split (linear for gates, tiled for logits)
__global__ void k_hnew(const float* __restrict__ gi, const float* __restrict__ gh,
                       const float* __restrict__ b_ih, const float* __restrict__ b_hh,
                       const float* __restrict__ hprev, float* __restrict__ hnext,
                       float* __restrict__ hy, _Float16* __restrict__ h_hi,
                       _Float16* __restrict__ h_lo, _Float16* __restrict__ ht, int t) {
  int idx = blockIdx.x * blockDim.x + threadIdx.x;
  if (idx >= B * HID) return;
  int b = idx / HID, i = idx % HID;
  float ir = gi[b * G3 + i]            + b_ih[i];
  float iz = gi[b * G3 + HID + i]      + b_ih[HID + i];
  float in_ = gi[b * G3 + 2 * HID + i] + b_ih[2 * HID + i];
  float hr = gh[b * G3 + i]            + b_hh[i];
  float hz = gh[b * G3 + HID + i]      + b_hh[HID + i];
  float hn = gh[b * G3 + 2 * HID + i]  + b_hh[2 * HID + i];
  float r  = 1.0f / (1.0f + expf(-(ir + hr)));
  float zg = 1.0f / (1.0f + expf(-(iz + hz)));
  float n  = tanhf(in_ + r * hn);
  float h  = (1.0f - zg) * n + zg * hprev[idx];
  hnext[idx] = h;
  hy[(size_t)b * SEQ * HID + (size_t)t * HID + i] = h;
  hl16 rr = split16(h, 8.0f);
  h_hi[b * KP + i] = rr.hi;
  h_lo[b * KP + i] = rr.lo;
  // tiled image for k_logits8: c=b>>7 (128-row halves), row=b&127,
  // kt=i>>5, kc=(i>>3)&3, e=i&7
  int c = b >> 7, row = b & 127;
  size_t tb = (size_t)c * TILE_STRIDE + (size_t)(i >> 5) * 2 * CHUNK
            + ((((i >> 3) & 3) * 128 + row) * 8) + (i & 7);
  ht[tb] = rr.hi;
  ht[tb + CHUNK] = rr.lo;
}

// ---------------- MFMA logits v9: RNG fused into GEMM loop (q[32] in VGPR) ----
// r11 pipeline (3-buf LDS h + counted vmcnt(4) + W regs distance-2 + setprio)
// with the epilogue's threefry+gumbel PRE-COMPUTED during the K-loop: q[s] =
// out_b[v] + gumbel(b,v) is acc-independent pure-VALU work that co-issues with
// the MFMA pipe (m114). Loop fully unrolled (22 static STEPs) so q[32] has
// compile-time indices (rule #20). Epilogue: 32x {fma, pack, max}.
__global__ __launch_bounds__(256, 2)
void k_logits8(const _Float16* __restrict__ wt, const _Float16* __restrict__ ht,
               const float* __restrict__ out_b, const uint32_t* __restrict__ keys,
               unsigned long long* __restrict__ slot, int t) {
  const int item = (blockIdx.x & 7) * 197 + (blockIdx.x >> 3);  // XCD-chunked
  if (item >= NIT5) return;
  const int p = item >> 2, vh = (item >> 1) & 1, c = item & 1;

  __shared__ float4 ldsh[3][1024];   // [buf][part*512 + kc*128 + row]
  const int tid = threadIdx.x, lane = tid & 63, wid = tid >> 6;
  const int wv = wid >> 1, wb = wid & 1;
  const int lq = lane >> 4, lr = lane & 15;

  const _Float16* __restrict__ wp = wt + (size_t)p * TILE_STRIDE;
  const _Float16* __restrict__ hp = ht + (size_t)c * TILE_STRIDE;

  const int wslot = lq * 128 + vh * 64 + wv * 32 + lr;   // + fv*16
  const int hslot = lq * 128 + wb * 64 + lr;             // + fb*16 (+part*512)
  const int vbase0 = p * 128 + vh * 64 + wv * 32;
  const int bbase0 = c * 128 + wb * 64 + lr;
  const uint32_t key0 = keys[2 * t], key1 = keys[2 * t + 1];

  // out_b values for this lane's 8 distinct v (fv x r), reused across fb
  float ob[8];
#pragma unroll
  for (int fv = 0; fv < 2; ++fv)
#pragma unroll
    for (int r = 0; r < 4; ++r) {
      int v = vbase0 + fv * 16 + lq * 4 + r;
      ob[fv * 4 + r] = (v < VOCAB) ? out_b[v] : 0.0f;
    }

  f32x4 acc[2][4];
#pragma unroll
  for (int i = 0; i < 2; ++i)
#pragma unroll
    for (int j = 0; j < 4; ++j) acc[i][j] = (f32x4)0.0f;

  float q[32];          // per-sample out_b + gumbel; ALL indices compile-time
  half8 W0[4], W1[4], W2[4];

#define LOADW(W, ktv)                                                         \
  {                                                                           \
    const _Float16* bw = wp + (size_t)(ktv) * (2 * CHUNK);                    \
    _Pragma("unroll")                                                         \
    for (int fv = 0; fv < 2; ++fv) {                                          \
      W[fv * 2 + 0] = *(const half8*)(bw + (wslot + fv * 16) * 8);            \
      W[fv * 2 + 1] = *(const half8*)(bw + CHUNK + (wslot + fv * 16) * 8);    \
    }                                                                         \
  }
#define STAGEH(bf, ktv)                                                       \
  {                                                                           \
    const _Float16* bh = hp + (size_t)(ktv) * (2 * CHUNK);                    \
    _Pragma("unroll")                                                         \
    for (int j = 0; j < 4; ++j)                                               \
      gload_lds16(bh + (j * 256 + wid * 64 + lane) * 8,                       \
                  &ldsh[bf][j * 256 + wid * 64]);                             \
  }
#define MFMAB(W, BF)                                                          \
  _Pragma("unroll")                                                           \
  for (int fb = 0; fb < 4; ++fb) {                                            \
    half8 hhi = *(const half8*)&ldsh[BF][hslot + fb * 16];                    \
    half8 hlo = *(const half8*)&ldsh[BF][512 + hslot + fb * 16];              \
    _Pragma("unroll")                                                         \
    for (int fv = 0; fv < 2; ++fv) {                                          \
      acc[fv][fb] = __builtin_amdgcn_mfma_f32_16x16x32_f16(                   \
          W[fv * 2 + 0], hhi, acc[fv][fb], 0, 0, 0);                          \
      acc[fv][fb] = __builtin_amdgcn_mfma_f32_16x16x32_f16(                   \
          W[fv * 2 + 0], hlo, acc[fv][fb], 0, 0, 0);                          \
      acc[fv][fb] = __builtin_amdgcn_mfma_f32_16x16x32_f16(                   \
          W[fv * 2 + 1], hhi, acc[fv][fb], 0, 0, 0);                          \
    }                                                                         \
  }
// QS(s): pure-VALU gumbel precompute for sample s (s<32; s==32 -> no-op).
// sample s -> fb=s>>3, fv=(s>>2)&1, r=s&3
#define QS(s)                                                                 \
  if ((s) < 32) {                                                             \
    const int fb_ = (s) >> 3, fv_ = ((s) >> 2) & 1, r_ = (s) & 3;             \
    const int b_ = bbase0 + fb_ * 16;                                         \
    const int v_ = vbase0 + fv_ * 16 + lq * 4 + r_;                           \
    uint32_t o0_, o1_;                                                        \
    threefry2x32(key0, key1, 0u, (uint32_t)(b_ * VOCAB + v_), o0_, o1_);      \
    uint32_t bits_ = o0_ ^ o1_;                                               \
    float f_ = __uint_as_float((bits_ >> 9) | 0x3f800000u) - 1.0f;            \
    float u_ = fmaxf(f_, 1.17549435e-38f);                                    \
    q[(s)] = ob[fv_ * 4 + r_] - __logf(-__logf(u_));                          \
  }
#define STEP(ktv, BC, BP, WCUR, WNEW, S0, S1)                                 \
  {                                                                           \
    asm volatile("s_waitcnt vmcnt(4)" ::: "memory");                          \
    __builtin_amdgcn_sched_barrier(0);                                        \
    __builtin_amdgcn_s_barrier();                                             \
    __builtin_amdgcn_sched_barrier(0);                                        \
    if ((ktv) + 2 < NKT) {                                                    \
      STAGEH(BP, (ktv) + 2)                                                   \
      LOADW(WNEW, (ktv) + 2)                                                  \
    }                                                                         \
    __builtin_amdgcn_s_setprio(1);                                            \
    MFMAB(WCUR, BC)                                                           \
    __builtin_amdgcn_s_setprio(0);                                            \
    QS(S0)                                                                    \
    QS(S1)                                                                    \
  }

  STAGEH(0, 0)
  STAGEH(1, 1)
  LOADW(W0, 0)
  LOADW(W1, 1)
  STEP(0, 0, 2, W0, W2, 0, 1)
  STEP(1, 1, 0, W1, W0, 2, 3)
  STEP(2, 2, 1, W2, W1, 4, 5)
  STEP(3, 0, 2, W0, W2, 6, 7)
  STEP(4, 1, 0, W1, W0, 8, 9)
  STEP(5, 2, 1, W2, W1, 10, 11)
  STEP(6, 0, 2, W0, W2, 12, 13)
  STEP(7, 1, 0, W1, W0, 14, 15)
  STEP(8, 2, 1, W2, W1, 16, 17)
  STEP(9, 0, 2, W0, W2, 18, 19)
  STEP(10, 1, 0, W1, W0, 20, 32)
  STEP(11, 2, 1, W2, W1, 21, 32)
  STEP(12, 0, 2, W0, W2, 22, 32)
  STEP(13, 1, 0, W1, W0, 23, 32)
  STEP(14, 2, 1, W2, W1, 24, 32)
  STEP(15, 0, 2, W0, W2, 25, 32)
  STEP(16, 1, 0, W1, W0, 26, 32)
  STEP(17, 2, 1, W2, W1, 27, 32)
  STEP(18, 0, 2, W0, W2, 28, 32)
  STEP(19, 1, 0, W1, W0, 29, 32)
  STEP(20, 2, 1, W2, W1, 30, 32)
  STEP(21, 0, 2, W0, W2, 31, 32)
#undef STEP
#undef QS
#undef LOADW
#undef STAGEH
#undef MFMAB

  // short epilogue: score = acc*c2 + q; pack; reduce; atomicMax
  const float c2 = 1.0f / 512.0f;
#pragma unroll
  for (int fb = 0; fb < 4; ++fb) {
    const int b = bbase0 + fb * 16;
    unsigned long long best = 0ull;
#pragma unroll
    for (int fv = 0; fv < 2; ++fv) {
#pragma unroll
      for (int r = 0; r < 4; ++r) {
        int v = vbase0 + fv * 16 + lq * 4 + r;
        if (v < VOCAB) {
          float sc = acc[fv][fb][r] * c2 + q[fb * 8 + fv * 4 + r];
          uint32_t us = __float_as_uint(sc);
          us = (us & 0x80000000u) ? ~us : (us | 0x80000000u);
          unsigned long long cand =
              ((unsigned long long)us << 32) | (uint32_t)(~(uint32_t)v);
          if (cand > best) best = cand;
        }
      }
    }
    unsigned long long o;
    o = __shfl_xor(best, 16, 64); if (o > best) best = o;
    o = __shfl_xor(best, 32, 64); if (o > best) best = o;
    if (lq == 0) atomicMax(&slot[b], best);
  }
}

// ---------------- fp32 logits fallback ----------------
#define WPITCH 68
#define HPITCH 260
__global__ __launch_bounds__(256)
void k_logits_f32(const float* __restrict__ h, const float* __restrict__ out_w,
                  const float* __restrict__ out_b, const uint32_t* __restrict__ keys,
                  unsigned long long* __restrict__ slot, int t) {
  __shared__ float w_lds[20][WPITCH];
  __shared__ float h_lds[20][HPITCH];
  const int vbase = blockIdx.x * 64;
  const int tid = threadIdx.x;
  const int tv = tid % 8, tb = tid / 8;
  float acc[8][8];
#pragma unroll
  for (int i = 0; i < 8; ++i)
#pragma unroll
    for (int j = 0; j < 8; ++j) acc[i][j] = 0.f;

  for (int k0 = 0; k0 < HID; k0 += 20) {
    for (int idx = tid; idx < 64 * 20; idx += 256) {
      int vv = idx / 20, kk = idx % 20;
      int v = vbase + vv;
      w_lds[kk][vv] = (v < VOCAB) ? out_w[(size_t)v * HID + k0 + kk] : 0.0f;
    }
    for (int idx = tid; idx < 256 * 20; idx += 256) {
      int bb = idx / 20, kk = idx % 20;
      h_lds[kk][bb] = h[bb * HID + k0 + kk];
    }
    __syncthreads();
#pragma unroll
    for (int kk = 0; kk < 20; ++kk) {
      float wv[8], hv[8];
      *(float4*)&wv[0] = *(const float4*)&w_lds[kk][tv * 8];
      *(float4*)&wv[4] = *(const float4*)&w_lds[kk][tv * 8 + 4];
      *(float4*)&hv[0] = *(const float4*)&h_lds[kk][tb * 8];
      *(float4*)&hv[4] = *(const float4*)&h_lds[kk][tb * 8 + 4];
#pragma unroll
      for (int iv = 0; iv < 8; ++iv)
#pragma unroll
        for (int ib = 0; ib < 8; ++ib) acc[iv][ib] += wv[iv] * hv[ib];
    }
    __syncthreads();
  }

  const uint32_t key0 = keys[2 * t], key1 = keys[2 * t + 1];
#pragma unroll
  for (int ib = 0; ib < 8; ++ib) {
    const int b = tb * 8 + ib;
    unsigned long long best = 0ull;
#pragma unroll
    for (int iv = 0; iv < 8; ++iv) {
      int v = vbase + tv * 8 + iv;
      if (v >= VOCAB) continue;
      unsigned long long cand = gumbel_pack(acc[iv][ib] + out_b[v], key0, key1, b, v);
      if (cand > best) best = cand;
    }
#pragma unroll
    for (int off = 1; off < 8; off <<= 1) {
      unsigned long long other = __shfl_xor(best, off, 64);
      if (other > best) best = other;
    }
    if (tv == 0) atomicMax(&slot[b], best);
  }
}

// ---------------- token extraction + emb gather/split ----------------
__global__ void k_tok2(const unsigned long long* __restrict__ slot,
                       const float* __restrict__ emb_w,
                       int* __restrict__ tok_next, float* __restrict__ y_out,
                       _Float16* __restrict__ xc_hi, _Float16* __restrict__ xc_lo,
                       int t, int full) {
  const int b = blockIdx.x;
  const int c = threadIdx.x;   // 128 threads
  unsigned long long p = slot[b];
  uint32_t v = ~((uint32_t)(p & 0xFFFFFFFFull));
  if (c == 0) {
    tok_next[b] = (int)v;
    y_out[b * SEQ + t] = (float)v;
  }
  if (!full) return;
  if (c < 75) {
    float4 xv = *(const float4*)&emb_w[(size_t)v * EMB + c * 4];
    half4 hi, lo;
    hl16 r0 = split16(xv.x, 8.0f); hi[0] = r0.hi; lo[0] = r0.lo;
    hl16 r1 = split16(xv.y, 8.0f); hi[1] = r1.hi; lo[1] = r1.lo;
    hl16 r2 = split16(xv.z, 8.0f); hi[2] = r2.hi; lo[2] = r2.lo;
    hl16 r3 = split16(xv.w, 8.0f); hi[3] = r3.hi; lo[3] = r3.lo;
    *(half4*)&xc_hi[b * KIH + c * 4] = hi;
    *(half4*)&xc_lo[b * KIH + c * 4] = lo;
  } else if (c < 80) {
    *(half4*)&xc_hi[b * KIH + c * 4] = (half4)(_Float16)0.0f;
    *(half4*)&xc_lo[b * KIH + c * 4] = (half4)(_Float16)0.0f;
  }
}

// ---------------- host launch ----------------
extern "C" void kernel_launch(void* const* d_in, const int* in_sizes, int n_in,
                              void* d_out, int out_size, void* d_ws, size_t ws_size,
                              hipStream_t stream) {
  const float* z      = (const float*)d_in[0];
  const int*   l      = (const int*)  d_in[1];
  const float* emb_w  = (const float*)d_in[2];
  const float* attr_w = (const float*)d_in[3];
  const float* W_ih   = (const float*)d_in[4];
  const float* W_hh   = (const float*)d_in[5];
  const float* b_ih   = (const float*)d_in[6];
  const float* b_hh   = (const float*)d_in[7];
  const float* out_w  = (const float*)d_in[8];
  const float* out_b  = (const float*)d_in[9];

  float* hy    = (float*)d_out;
  float* y_out = (float*)d_out + HY_ELEMS;

  char* ws = (char*)d_ws;
  size_t off = 0;
  uint32_t* keys            = (uint32_t*)(ws + off);           off += 256;
  unsigned long long* slots = (unsigned long long*)(ws + off); off += (size_t)MAXLEN * B * 8;
  int* tokbuf               = (int*)(ws + off);                off += (size_t)32 * B * 4;
  float* hbuf               = (float*)(ws + off);              off += (size_t)2 * B * HID * 4;
  float* gi                 = (float*)(ws + off);              off += (size_t)B * G3 * 4;
  float* gh                 = (float*)(ws + off);              off += (size_t)B * G3 * 4;
  _Float16* h_hi            = (_Float16*)(ws + off);           off += (size_t)B * KP * 2;
  _Float16* h_lo            = (_Float16*)(ws + off);           off += (size_t)B * KP * 2;
  _Float16* ht              = (_Float16*)(ws + off);           off += (size_t)2 * TILE_STRIDE * 2;
  _Float16* wt              = (_Float16*)(ws + off);           off += (size_t)NVT * TILE_STRIDE * 2;
  const size_t tier1_end = off;
  _Float16* wih_hi          = (_Float16*)(ws + off);           off += (size_t)MPAD * KIH * 2;
  _Float16* wih_lo          = (_Float16*)(ws + off);           off += (size_t)MPAD * KIH * 2;
  _Float16* whh_hi          = (_Float16*)(ws + off);           off += (size_t)MPAD * KP * 2;
  _Float16* whh_lo          = (_Float16*)(ws + off);           off += (size_t)MPAD * KP * 2;
  _Float16* x0_hi           = (_Float16*)(ws + off);           off += (size_t)B * KIH * 2;
  _Float16* x0_lo           = (_Float16*)(ws + off);           off += (size_t)B * KIH * 2;
  _Float16* xe_hi           = (_Float16*)(ws + off);           off += (size_t)B * KIH * 2;
  _Float16* xe_lo           = (_Float16*)(ws + off);           off += (size_t)B * KIH * 2;
  _Float16* xc_hi           = (_Float16*)(ws + off);           off += (size_t)B * KIH * 2;
  _Float16* xc_lo           = (_Float16*)(ws + off);           off += (size_t)B * KIH * 2;
  const size_t tier2_end = off;
  const int tier = (ws_size >= tier2_end) ? 2 : ((ws_size >= tier1_end) ? 1 : 0);

  k_init<<<(B * HID + 255) / 256, 256, 0, stream>>>(
      z, l, attr_w, emb_w, hbuf, keys, slots, tokbuf, y_out, h_hi, h_lo, ht,
      x0_hi, x0_lo, xe_hi, xe_lo, (tier == 2) ? 1 : 0);

  if (tier >= 1) {
    size_t tot = (size_t)NVT * NKT * 1024;
    k_wsplit<<<(int)((tot + 255) / 256), 256, 0, stream>>>(out_w, wt);
  }
  if (tier == 2) {
    int tih = MPAD * KIH / 4, thh = MPAD * KP / 4;
    k_gwsplit<<<(tih + 255) / 256, 256, 0, stream>>>(W_ih, wih_hi, wih_lo, G3, EMB, KIH, tih);
    k_gwsplit<<<(thh + 255) / 256, 256, 0, stream>>>(W_hh, whh_hi, whh_lo, G3, HID, KP, thh);
  }

  for (int t = 0; t <= MAXLEN; ++t) {
    float* hprev = hbuf + (t % 2) * B * HID;
    float* hnext = hbuf + ((t + 1) % 2) * B * HID;

    if (tier == 2) {
      const _Float16* xh = (t == 0) ? x0_hi : ((t == MAXLEN) ? xe_hi : xc_hi);
      const _Float16* xl = (t == 0) ? x0_lo : ((t == MAXLEN) ? xe_lo : xc_lo);
      dim3 g2(33, 4, 2);
      k_gates2<<<g2, 256, 0, stream>>>(wih_hi, wih_lo, whh_hi, whh_lo,
                                       xh, xl, h_hi, h_lo, gi, gh);
    } else {
      const int* tok_t = tokbuf + ((t == MAXLEN) ? 31 : t) * B;
      dim3 ggrid(66, 8, 2);
      k_gates<<<ggrid, 256, 0, stream>>>(W_ih, W_hh, emb_w, hprev, tok_t, gi, gh);
    }
    k_hnew<<<(B * HID + 255) / 256, 256, 0, stream>>>(gi, gh, b_ih, b_hh, hprev,
                                                      hnext, hy, h_hi, h_lo, ht, t);
    if (t < MAXLEN) {
      if (tier >= 1) {
        k_logits8<<<NBLK5, 256, 0, stream>>>(wt, ht, out_b, keys,
                                             slots + (size_t)t * B, t);
      } else {
        k_logits_f32<<<(VOCAB + 63) / 64, 256, 0, stream>>>(hnext, out_w, out_b, keys,
                                                            slots + (size_t)t * B, t);
      }
      k_tok2<<<B, 128, 0, stream>>>(slots + (size_t)t * B, emb_w,
                                    tokbuf + (t + 1) * B, y_out, xc_hi, xc_lo,
                                    t, (tier == 2) ? 1 : 0);
    }
  }
}

// Round 14
// 3562.139 us; speedup vs baseline: 1.0753x; 1.0169x over previous
//
#include <hip/hip_runtime.h>
#include <stdint.h>

#define VOCAB 50257
#define B 256
#define EMB 300
#define HID 700
#define G3 2100          // 3*HID
#define ZDIM 500
#define ATTR_EMBD 200
#define MAXLEN 30
#define SEQ 31           // MAXLEN+1
#define HY_ELEMS (B*SEQ*HID)
#define KP 704           // HID padded to mult of 32
#define NKT 22           // KP/32 k-tiles
#define KIH 320          // EMB padded to mult of 32
#define VPAD 50304       // VOCAB padded to mult of 128 (393*128)
#define NVT 393          // VPAD/128
#define MPAD 2112        // G3 padded to 33*64
#define SOS_IDX 1
#define EOS_IDX 2
// tiled chunk: per (tile, kt): [part(2)][4096 halves]; half idx = (kc*128+row)*8+e
#define CHUNK 4096
#define TILE_STRIDE ((size_t)NKT * 2 * CHUNK)   // halves per v-panel / h half-tile
// logits grid: items = (panel, v-half, b-half) = 393*2*2 = 1572; 8 XCD x 197
#define NIT5 1572
#define NBLK5 1576

typedef _Float16 half8 __attribute__((ext_vector_type(8)));
typedef _Float16 half4 __attribute__((ext_vector_type(4)));
typedef float f32x4 __attribute__((ext_vector_type(4)));

// ---------------- global_load_lds helper (16B per lane, dest = wave base + lane*16)
typedef const __attribute__((address_space(1))) void* gas1_t;
typedef __attribute__((address_space(3))) void* las3_t;
__device__ __forceinline__ void gload_lds16(const void* g, void* l) {
  __builtin_amdgcn_global_load_lds((gas1_t)g, (las3_t)l, 16, 0, 0);
}

// ---------------- threefry2x32 (JAX-exact, 20 rounds) ----------------
__device__ __forceinline__ uint32_t rotl32(uint32_t x, int r) {
  return (x << r) | (x >> (32 - r));
}

__device__ __forceinline__ void threefry2x32(uint32_t k0, uint32_t k1,
                                             uint32_t x0, uint32_t x1,
                                             uint32_t& o0, uint32_t& o1) {
  const uint32_t ks2 = k0 ^ k1 ^ 0x1BD11BDAu;
  x0 += k0; x1 += k1;
#define TF_R4(a, b, c, d)                                     \
  x0 += x1; x1 = rotl32(x1, a); x1 ^= x0;                     \
  x0 += x1; x1 = rotl32(x1, b); x1 ^= x0;                     \
  x0 += x1; x1 = rotl32(x1, c); x1 ^= x0;                     \
  x0 += x1; x1 = rotl32(x1, d); x1 ^= x0;
  TF_R4(13, 15, 26, 6)  x0 += k1;  x1 += ks2 + 1u;
  TF_R4(17, 29, 16, 24) x0 += ks2; x1 += k0 + 2u;
  TF_R4(13, 15, 26, 6)  x0 += k0;  x1 += k1 + 3u;
  TF_R4(17, 29, 16, 24) x0 += k1;  x1 += ks2 + 4u;
  TF_R4(13, 15, 26, 6)  x0 += ks2; x1 += k0 + 5u;
#undef TF_R4
  o0 = x0; o1 = x1;
}

__device__ __forceinline__ unsigned long long gumbel_pack(float s, uint32_t key0,
                                                          uint32_t key1, int b, int v) {
  uint32_t j = (uint32_t)(b * VOCAB + v);
  uint32_t o0, o1;
  threefry2x32(key0, key1, 0u, j, o0, o1);
  uint32_t bits = o0 ^ o1;
  float f = __uint_as_float((bits >> 9) | 0x3f800000u) - 1.0f;
  float u = fmaxf(f, 1.17549435e-38f);
  float g = -__logf(-__logf(u));
  s += g;
  uint32_t us = __float_as_uint(s);
  us = (us & 0x80000000u) ? ~us : (us | 0x80000000u);
  return ((unsigned long long)us << 32) | (uint32_t)(~(uint32_t)v);
}

// split helper: val*scale -> {fp16 hi, fp16 lo = raw residual (UNSCALED)}.
struct hl16 { _Float16 hi, lo; };
__device__ __forceinline__ hl16 split16(float val, float scale) {
  float s = val * scale;
  _Float16 h = (_Float16)s;
  hl16 r;
  r.hi = h;
  r.lo = (_Float16)(s - (float)h);
  return r;
}

// ---------------- init ----------------
__global__ void k_init(const float* __restrict__ z, const int* __restrict__ l,
                       const float* __restrict__ attr_w, const float* __restrict__ emb_w,
                       float* __restrict__ hbuf0, uint32_t* __restrict__ keys,
                       unsigned long long* __restrict__ slots,
                       int* __restrict__ tok, float* __restrict__ y_out,
                       _Float16* __restrict__ h_hi, _Float16* __restrict__ h_lo,
                       _Float16* __restrict__ ht,
                       _Float16* __restrict__ x0_hi, _Float16* __restrict__ x0_lo,
                       _Float16* __restrict__ xe_hi, _Float16* __restrict__ xe_lo,
                       int full) {
  int idx = blockIdx.x * blockDim.x + threadIdx.x;
  if (idx < B * HID) {
    int b = idx / HID, i = idx % HID;
    float v = (i < ZDIM) ? z[b * ZDIM + i]
                         : attr_w[l[b] * ATTR_EMBD + (i - ZDIM)];
    hbuf0[idx] = v;
    hl16 r = split16(v, 8.0f);
    h_hi[b * KP + i] = r.hi;
    h_lo[b * KP + i] = r.lo;
  }
  if (idx < MAXLEN) {
    uint32_t o0, o1;
    threefry2x32(0u, 42u, 0u, (uint32_t)idx, o0, o1);
    keys[2 * idx] = o0; keys[2 * idx + 1] = o1;
  }
  if (idx < MAXLEN * B) slots[idx] = 0ull;
  if (idx < B) {
    tok[idx] = SOS_IDX;
    tok[31 * B + idx] = EOS_IDX;
    y_out[idx * SEQ + MAXLEN] = 2.0f;
  }
  if (idx < B * 4) {  // zero k-pad (700..703) of linear + tiled h (kt=21, kc=3)
    int b = idx >> 2, k = HID + (idx & 3);
    h_hi[b * KP + k] = (_Float16)0.0f;
    h_lo[b * KP + k] = (_Float16)0.0f;
    int c = b >> 7, row = b & 127, e = k & 7;
    size_t tb = (size_t)c * TILE_STRIDE + (size_t)21 * 2 * CHUNK
              + (3 * 128 + row) * 8 + e;
    ht[tb] = (_Float16)0.0f;
    ht[tb + CHUNK] = (_Float16)0.0f;
  }
  if (full && idx < KIH) {
    float v0 = (idx < EMB) ? emb_w[SOS_IDX * EMB + idx] : 0.0f;
    float ve = (idx < EMB) ? emb_w[EOS_IDX * EMB + idx] : 0.0f;
    hl16 r0 = split16(v0, 8.0f);
    hl16 re = split16(ve, 8.0f);
    for (int b = 0; b < B; ++b) {  // broadcast rows (all batches share SOS/EOS)
      x0_hi[b * KIH + idx] = r0.hi; x0_lo[b * KIH + idx] = r0.lo;
      xe_hi[b * KIH + idx] = re.hi; xe_lo[b * KIH + idx] = re.lo;
    }
  }
}

// ---------------- logits w split -> TILED image; READ-COALESCED mapping ----
__global__ void k_wsplit(const float* __restrict__ out_w, _Float16* __restrict__ wt) {
  size_t idx = (size_t)blockIdx.x * blockDim.x + threadIdx.x;
  if (idx >= (size_t)VPAD * (KP / 4)) return;
  int v = (int)(idx / (KP / 4));
  int k = (int)(idx % (KP / 4)) * 4;
  float x[4];
  if (v < VOCAB && k + 3 < HID) {
    const float4 xv = *(const float4*)&out_w[(size_t)v * HID + k];
    x[0] = xv.x; x[1] = xv.y; x[2] = xv.z; x[3] = xv.w;
  } else {
#pragma unroll
    for (int j = 0; j < 4; ++j)
      x[j] = (v < VOCAB && k + j < HID) ? out_w[(size_t)v * HID + k + j] : 0.0f;
  }
  half4 hi, lo;
#pragma unroll
  for (int j = 0; j < 4; ++j) {
    hl16 r = split16(x[j], 64.0f);
    hi[j] = r.hi; lo[j] = r.lo;
  }
  int p = v >> 7, row = v & 127;
  int kt = k >> 5, kc = (k >> 3) & 3, e0 = k & 7;   // e0 in {0,4}
  size_t base = (size_t)p * TILE_STRIDE + (size_t)kt * 2 * CHUNK
              + (kc * 128 + row) * 8 + e0;
  *(half4*)&wt[base] = hi;
  *(half4*)&wt[base + CHUNK] = lo;
}

// ---------------- generic gate-weight split (Msrc x Ksrc -> MPAD x Kpad) ----------------
__global__ void k_gwsplit(const float* __restrict__ src, _Float16* __restrict__ hi,
                          _Float16* __restrict__ lo, int Msrc, int Ksrc, int Kpad,
                          int tot4) {
  int idx = blockIdx.x * blockDim.x + threadIdx.x;
  if (idx >= tot4) return;
  size_t i4 = (size_t)idx * 4;
  int m = (int)(i4 / Kpad), k = (int)(i4 % Kpad);
  half4 h, l;
#pragma unroll
  for (int j = 0; j < 4; ++j) {
    float x = (m < Msrc && k + j < Ksrc) ? src[(size_t)m * Ksrc + k + j] : 0.0f;
    hl16 r = split16(x, 64.0f);
    h[j] = r.hi; l[j] = r.lo;
  }
  *(half4*)&hi[i4] = h;
  *(half4*)&lo[i4] = l;
}

// ---------------- MFMA gates: 64j x 64b blocks, 4 waves (32x32), merged acc ----
__global__ __launch_bounds__(256, 4)
void k_gates2(const _Float16* __restrict__ wih_hi, const _Float16* __restrict__ wih_lo,
              const _Float16* __restrict__ whh_hi, const _Float16* __restrict__ whh_lo,
              const _Float16* __restrict__ x_hi, const _Float16* __restrict__ x_lo,
              const _Float16* __restrict__ h_hi, const _Float16* __restrict__ h_lo,
              float* __restrict__ gi, float* __restrict__ gh) {
  const int zz = blockIdx.z;
  const _Float16* __restrict__ Whi = zz ? whh_hi : wih_hi;
  const _Float16* __restrict__ Wlo = zz ? whh_lo : wih_lo;
  const _Float16* __restrict__ Xhi = zz ? h_hi : x_hi;
  const _Float16* __restrict__ Xlo = zz ? h_lo : x_lo;
  const int Kz = zz ? KP : KIH;
  float* __restrict__ out = zz ? gh : gi;

  const int jbase = blockIdx.x * 64;
  const int bbase = blockIdx.y * 64;
  __shared__ float4 lds[2][4][256];   // [buf][whi,wlo,xhi,xlo][kc*64+row]
  const int tid = threadIdx.x, lane = tid & 63, wid = tid >> 6;
  const int wj = wid >> 1, wb2 = wid & 1;
  const size_t wrow = (size_t)(jbase + lane) * Kz;   // stage: kc=wid, row=lane
  const size_t xrow = (size_t)(bbase + lane) * Kz;

  f32x4 acc[2][2];
#pragma unroll
  for (int i = 0; i < 2; ++i)
#pragma unroll
    for (int j = 0; j < 2; ++j) acc[i][j] = (f32x4)0.0f;

#define GSTAGE(bf, k0)                                                   \
  {                                                                      \
    gload_lds16(Whi + wrow + (k0) + wid * 8, &lds[bf][0][wid * 64]);     \
    gload_lds16(Wlo + wrow + (k0) + wid * 8, &lds[bf][1][wid * 64]);     \
    gload_lds16(Xhi + xrow + (k0) + wid * 8, &lds[bf][2][wid * 64]);     \
    gload_lds16(Xlo + xrow + (k0) + wid * 8, &lds[bf][3][wid * 64]);     \
  }

  const int nt = Kz / 32;
  GSTAGE(0, 0)
  for (int kt = 0; kt < nt; ++kt) {
    const int cur = kt & 1;
    __syncthreads();                       // drains staged loads for buf[cur]
    if (kt + 1 < nt) GSTAGE(cur ^ 1, (kt + 1) * 32)
    const int kcf = (lane >> 4) * 64 + (lane & 15);
    half8 a_hi[2], a_lo[2];
#pragma unroll
    for (int fv = 0; fv < 2; ++fv) {
      int s = kcf + wj * 32 + fv * 16;
      a_hi[fv] = *(const half8*)&lds[cur][0][s];
      a_lo[fv] = *(const half8*)&lds[cur][1][s];
    }
#pragma unroll
    for (int fb = 0; fb < 2; ++fb) {
      int s = kcf + wb2 * 32 + fb * 16;
      half8 b_hi = *(const half8*)&lds[cur][2][s];
      half8 b_lo = *(const half8*)&lds[cur][3][s];
#pragma unroll
      for (int fv = 0; fv < 2; ++fv) {
        acc[fv][fb] = __builtin_amdgcn_mfma_f32_16x16x32_f16(a_hi[fv], b_hi,
                                                             acc[fv][fb], 0, 0, 0);
        acc[fv][fb] = __builtin_amdgcn_mfma_f32_16x16x32_f16(a_hi[fv], b_lo,
                                                             acc[fv][fb], 0, 0, 0);
        acc[fv][fb] = __builtin_amdgcn_mfma_f32_16x16x32_f16(a_lo[fv], b_hi,
                                                             acc[fv][fb], 0, 0, 0);
      }
    }
  }
#undef GSTAGE

  const float c2 = 1.0f / 512.0f;
#pragma unroll
  for (int fb = 0; fb < 2; ++fb) {
    const int b = bbase + wb2 * 32 + fb * 16 + (lane & 15);
#pragma unroll
    for (int fv = 0; fv < 2; ++fv) {
#pragma unroll
      for (int r = 0; r < 4; ++r) {
        int j = jbase + wj * 32 + fv * 16 + (lane >> 4) * 4 + r;
        if (j < G3) out[b * G3 + j] = acc[fv][fb][r] * c2;
      }
    }
  }
}

// ---------------- fp32 gates fallback ----------------
__global__ void k_gates(const float* __restrict__ W_ih, const float* __restrict__ W_hh,
                        const float* __restrict__ emb_w, const float* __restrict__ hprev,
                        const int* __restrict__ tok,
                        float* __restrict__ gi, float* __restrict__ gh) {
  const int zz = blockIdx.z;
  const float* __restrict__ W = zz ? W_hh : W_ih;
  const int K = zz ? HID : EMB;
  float* __restrict__ out = zz ? gh : gi;
  __shared__ float w_lds[20][36];
  __shared__ float xh_lds[20][36];
  const int jbase = blockIdx.x * 32;
  const int bbase = blockIdx.y * 32;
  const int tid = threadIdx.x;
  const int tj = tid % 16, tb = tid / 16;
  float a00 = 0.f, a01 = 0.f, a10 = 0.f, a11 = 0.f;
  for (int k0 = 0; k0 < K; k0 += 20) {
    for (int idx = tid; idx < 640; idx += 256) {
      int col = idx / 20, kk = idx % 20;
      int j = jbase + col;
      w_lds[kk][col] = (j < G3) ? W[j * K + k0 + kk] : 0.0f;
      int b = bbase + col;
      float xv;
      if (zz) xv = hprev[b * HID + k0 + kk];
      else    xv = emb_w[tok[b] * EMB + k0 + kk];
      xh_lds[kk][col] = xv;
    }
    __syncthreads();
#pragma unroll
    for (int kk = 0; kk < 20; ++kk) {
      float w0 = w_lds[kk][tj * 2], w1 = w_lds[kk][tj * 2 + 1];
      float h0 = xh_lds[kk][tb * 2], h1 = xh_lds[kk][tb * 2 + 1];
      a00 += w0 * h0; a01 += w0 * h1;
      a10 += w1 * h0; a11 += w1 * h1;
    }
    __syncthreads();
  }
  int j0 = jbase + tj * 2, b0 = bbase + tb * 2;
  if (j0 < G3)     { out[b0 * G3 + j0] = a00;     out[(b0 + 1) * G3 + j0] = a01; }
  if (j0 + 1 < G3) { out[b0 * G3 + j0 + 1] = a10; out[(b0 + 1) * G3 + j0 + 1] = a11; }
}

// ---------------- pointwise GRU update + h fp16-split (linear for gates, tiled for logits)
__global__ void k_hnew(const float* __restrict__ gi, const float* __restrict__ gh,
                       const float* __restrict__ b_ih, const float* __restrict__ b_hh,
                       const float* __restrict__ hprev, float* __restrict__ hnext,
                       float* __restrict__ hy, _Float16* __restrict__ h_hi,
                       _Float16* __restrict__ h_lo, _Float16* __restrict__ ht, int t) {
  int idx = blockIdx.x * blockDim.x + threadIdx.x;
  if (idx >= B * HID) return;
  int b = idx / HID, i = idx % HID;
  float ir = gi[b * G3 + i]            + b_ih[i];
  float iz = gi[b * G3 + HID + i]      + b_ih[HID + i];
  float in_ = gi[b * G3 + 2 * HID + i] + b_ih[2 * HID + i];
  float hr = gh[b * G3 + i]            + b_hh[i];
  float hz = gh[b * G3 + HID + i]      + b_hh[HID + i];
  float hn = gh[b * G3 + 2 * HID + i]  + b_hh[2 * HID + i];
  float r  = 1.0f / (1.0f + expf(-(ir + hr)));
  float zg = 1.0f / (1.0f + expf(-(iz + hz)));
  float n  = tanhf(in_ + r * hn);
  float h  = (1.0f - zg) * n + zg * hprev[idx];
  hnext[idx] = h;
  hy[(size_t)b * SEQ * HID + (size_t)t * HID + i] = h;
  hl16 rr = split16(h, 8.0f);
  h_hi[b * KP + i] = rr.hi;
  h_lo[b * KP + i] = rr.lo;
  // tiled image for k_logits10: c=b>>7 (128-row halves), row=b&127,
  // kt=i>>5, kc=(i>>3)&3, e=i&7
  int c = b >> 7, row = b & 127;
  size_t tb = (size_t)c * TILE_STRIDE + (size_t)(i >> 5) * 2 * CHUNK
            + ((((i >> 3) & 3) * 128 + row) * 8) + (i & 7);
  ht[tb] = rr.hi;
  ht[tb + CHUNK] = rr.lo;
}

// ---------------- MFMA logits v11: SAFE counted vmcnt(8) + 3 blocks/CU ----
// r13's vmcnt(12) raced: sched_barrier(0) fences only region BOUNDARIES; the
// compiler may order the 4 LW before the 4 SH within a region, so ops younger
// than SH(kt) at STEP(kt)'s wait ∈ [8,12]. vmcnt(8) is the max safe count
// under any intra-region order (the following region always contributes 8).
// Last step (21): preceding regions stage nothing -> younger can be 0 ->
// drain vmcnt(0) there (once, cheap).
__global__ __launch_bounds__(256, 3)
void k_logits10(const _Float16* __restrict__ wt, const _Float16* __restrict__ ht,
                const float* __restrict__ out_b, const uint32_t* __restrict__ keys,
                unsigned long long* __restrict__ slot, int t) {
  const int item = (blockIdx.x & 7) * 197 + (blockIdx.x >> 3);  // XCD-chunked
  if (item >= NIT5) return;
  const int p = item >> 2, vh = (item >> 1) & 1, c = item & 1;

  __shared__ float4 ldsh[3][1024];   // [buf][part*512 + kc*128 + row]
  const int tid = threadIdx.x, lane = tid & 63, wid = tid >> 6;
  const int wv = wid >> 1, wb = wid & 1;
  const int lq = lane >> 4, lr = lane & 15;

  const _Float16* __restrict__ wp = wt + (size_t)p * TILE_STRIDE;
  const _Float16* __restrict__ hp = ht + (size_t)c * TILE_STRIDE;

  const int wslot = lq * 128 + vh * 64 + wv * 32 + lr;   // + fv*16
  const int hslot = lq * 128 + wb * 64 + lr;             // + fb*16 (+part*512)
  const int vbase0 = p * 128 + vh * 64 + wv * 32;
  const int bbase0 = c * 128 + wb * 64 + lr;
  const uint32_t key0 = keys[2 * t], key1 = keys[2 * t + 1];

  // out_b values for this lane's 8 distinct v (fv x r), reused across fb
  float ob[8];
#pragma unroll
  for (int fv = 0; fv < 2; ++fv)
#pragma unroll
    for (int r = 0; r < 4; ++r) {
      int v = vbase0 + fv * 16 + lq * 4 + r;
      ob[fv * 4 + r] = (v < VOCAB) ? out_b[v] : 0.0f;
    }

  f32x4 acc[2][4];
#pragma unroll
  for (int i = 0; i < 2; ++i)
#pragma unroll
    for (int j = 0; j < 4; ++j) acc[i][j] = (f32x4)0.0f;

  float q[32];          // per-sample out_b + gumbel; ALL indices compile-time
  half8 W0[4], W1[4], W2[4];

#define LOADW(W, ktv)                                                         \
  {                                                                           \
    const _Float16* bw = wp + (size_t)(ktv) * (2 * CHUNK);                    \
    _Pragma("unroll")                                                         \
    for (int fv = 0; fv < 2; ++fv) {                                          \
      W[fv * 2 + 0] = *(const half8*)(bw + (wslot + fv * 16) * 8);            \
      W[fv * 2 + 1] = *(const half8*)(bw + CHUNK + (wslot + fv * 16) * 8);    \
    }                                                                         \
  }
#define STAGEH(bf, ktv)                                                       \
  {                                                                           \
    const _Float16* bh = hp + (size_t)(ktv) * (2 * CHUNK);                    \
    _Pragma("unroll")                                                         \
    for (int j = 0; j < 4; ++j)                                               \
      gload_lds16(bh + (j * 256 + wid * 64 + lane) * 8,                       \
                  &ldsh[bf][j * 256 + wid * 64]);                             \
  }
#define MFMAB(W, BF)                                                          \
  _Pragma("unroll")                                                           \
  for (int fb = 0; fb < 4; ++fb) {                                            \
    half8 hhi = *(const half8*)&ldsh[BF][hslot + fb * 16];                    \
    half8 hlo = *(const half8*)&ldsh[BF][512 + hslot + fb * 16];              \
    _Pragma("unroll")                                                         \
    for (int fv = 0; fv < 2; ++fv) {                                          \
      acc[fv][fb] = __builtin_amdgcn_mfma_f32_16x16x32_f16(                   \
          W[fv * 2 + 0], hhi, acc[fv][fb], 0, 0, 0);                          \
      acc[fv][fb] = __builtin_amdgcn_mfma_f32_16x16x32_f16(                   \
          W[fv * 2 + 0], hlo, acc[fv][fb], 0, 0, 0);                          \
      acc[fv][fb] = __builtin_amdgcn_mfma_f32_16x16x32_f16(                   \
          W[fv * 2 + 1], hhi, acc[fv][fb], 0, 0, 0);                          \
    }                                                                         \
  }
// QS(s): pure-VALU gumbel precompute for sample s (s<32; s==32 -> no-op).
// sample s -> fb=s>>3, fv=(s>>2)&1, r=s&3
#define QS(s)                                                                 \
  if ((s) < 32) {                                                             \
    const int fb_ = (s) >> 3, fv_ = ((s) >> 2) & 1, r_ = (s) & 3;             \
    const int b_ = bbase0 + fb_ * 16;                                         \
    const int v_ = vbase0 + fv_ * 16 + lq * 4 + r_;                           \
    uint32_t o0_, o1_;                                                        \
    threefry2x32(key0, key1, 0u, (uint32_t)(b_ * VOCAB + v_), o0_, o1_);      \
    uint32_t bits_ = o0_ ^ o1_;                                               \
    float f_ = __uint_as_float((bits_ >> 9) | 0x3f800000u) - 1.0f;            \
    float u_ = fmaxf(f_, 1.17549435e-38f);                                    \
    q[(s)] = ob[fv_ * 4 + r_] - __logf(-__logf(u_));                          \
  }
#define STEPN(ktv, BC, BP, WCUR, WNEW, S0, S1, VM)                            \
  {                                                                           \
    asm volatile("s_waitcnt vmcnt(" #VM ")" ::: "memory");                    \
    __builtin_amdgcn_sched_barrier(0);                                        \
    __builtin_amdgcn_s_barrier();                                             \
    __builtin_amdgcn_sched_barrier(0);                                        \
    if ((ktv) + 2 < NKT) {                                                    \
      STAGEH(BP, (ktv) + 2)                                                   \
      LOADW(WNEW, (ktv) + 2)                                                  \
    }                                                                         \
    __builtin_amdgcn_s_setprio(1);                                            \
    MFMAB(WCUR, BC)                                                           \
    __builtin_amdgcn_s_setprio(0);                                            \
    QS(S0)                                                                    \
    QS(S1)                                                                    \
  }

  STAGEH(0, 0)
  STAGEH(1, 1)
  LOADW(W0, 0)
  LOADW(W1, 1)
  STEPN(0, 0, 2, W0, W2, 0, 1, 8)
  STEPN(1, 1, 0, W1, W0, 2, 3, 8)
  STEPN(2, 2, 1, W2, W1, 4, 5, 8)
  STEPN(3, 0, 2, W0, W2, 6, 7, 8)
  STEPN(4, 1, 0, W1, W0, 8, 9, 8)
  STEPN(5, 2, 1, W2, W1, 10, 11, 8)
  STEPN(6, 0, 2, W0, W2, 12, 13, 8)
  STEPN(7, 1, 0, W1, W0, 14, 15, 8)
  STEPN(8, 2, 1, W2, W1, 16, 17, 8)
  STEPN(9, 0, 2, W0, W2, 18, 19, 8)
  STEPN(10, 1, 0, W1, W0, 20, 32, 8)
  STEPN(11, 2, 1, W2, W1, 21, 32, 8)
  STEPN(12, 0, 2, W0, W2, 22, 32, 8)
  STEPN(13, 1, 0, W1, W0, 23, 32, 8)
  STEPN(14, 2, 1, W2, W1, 24, 32, 8)
  STEPN(15, 0, 2, W0, W2, 25, 32, 8)
  STEPN(16, 1, 0, W1, W0, 26, 32, 8)
  STEPN(17, 2, 1, W2, W1, 27, 32, 8)
  STEPN(18, 0, 2, W0, W2, 28, 32, 8)
  STEPN(19, 1, 0, W1, W0, 29, 32, 8)
  STEPN(20, 2, 1, W2, W1, 30, 32, 8)
  STEPN(21, 0, 2, W0, W2, 31, 32, 0)
#undef STEPN
#undef QS
#undef LOADW
#undef STAGEH
#undef MFMAB

  // short epilogue: score = acc*c2 + q; pack; reduce; atomicMax
  const float c2 = 1.0f / 512.0f;
#pragma unroll
  for (int fb = 0; fb < 4; ++fb) {
    const int b = bbase0 + fb * 16;
    unsigned long long best = 0ull;
#pragma unroll
    for (int fv = 0; fv < 2; ++fv) {
#pragma unroll
      for (int r = 0; r < 4; ++r) {
        int v = vbase0 + fv * 16 + lq * 4 + r;
        if (v < VOCAB) {
          float sc = acc[fv][fb][r] * c2 + q[fb * 8 + fv * 4 + r];
          uint32_t us = __float_as_uint(sc);
          us = (us & 0x80000000u) ? ~us : (us | 0x80000000u);
          unsigned long long cand =
              ((unsigned long long)us << 32) | (uint32_t)(~(uint32_t)v);
          if (cand > best) best = cand;
        }
      }
    }
    unsigned long long o;
    o = __shfl_xor(best, 16, 64); if (o > best) best = o;
    o = __shfl_xor(best, 32, 64); if (o > best) best = o;
    if (lq == 0) atomicMax(&slot[b], best);
  }
}

// ---------------- fp32 logits fallback ----------------
#define WPITCH 68
#define HPITCH 260
__global__ __launch_bounds__(256)
void k_logits_f32(const float* __restrict__ h, const float* __restrict__ out_w,
                  const float* __restrict__ out_b, const uint32_t* __restrict__ keys,
                  unsigned long long* __restrict__ slot, int t) {
  __shared__ float w_lds[20][WPITCH];
  __shared__ float h_lds[20][HPITCH];
  const int vbase = blockIdx.x * 64;
  const int tid = threadIdx.x;
  const int tv = tid % 8, tb = tid / 8;
  float acc[8][8];
#pragma unroll
  for (int i = 0; i < 8; ++i)
#pragma unroll
    for (int j = 0; j < 8; ++j) acc[i][j] = 0.f;

  for (int k0 = 0; k0 < HID; k0 += 20) {
    for (int idx = tid; idx < 64 * 20; idx += 256) {
      int vv = idx / 20, kk = idx % 20;
      int v = vbase + vv;
      w_lds[kk][vv] = (v < VOCAB) ? out_w[(size_t)v * HID + k0 + kk] : 0.0f;
    }
    for (int idx = tid; idx < 256 * 20; idx += 256) {
      int bb = idx / 20, kk = idx % 20;
      h_lds[kk][bb] = h[bb * HID + k0 + kk];
    }
    __syncthreads();
#pragma unroll
    for (int kk = 0; kk < 20; ++kk) {
      float wv[8], hv[8];
      *(float4*)&wv[0] = *(const float4*)&w_lds[kk][tv * 8];
      *(float4*)&wv[4] = *(const float4*)&w_lds[kk][tv * 8 + 4];
      *(float4*)&hv[0] = *(const float4*)&h_lds[kk][tb * 8];
      *(float4*)&hv[4] = *(const float4*)&h_lds[kk][tb * 8 + 4];
#pragma unroll
      for (int iv = 0; iv < 8; ++iv)
#pragma unroll
        for (int ib = 0; ib < 8; ++ib) acc[iv][ib] += wv[iv] * hv[ib];
    }
    __syncthreads();
  }

  const uint32_t key0 = keys[2 * t], key1 = keys[2 * t + 1];
#pragma unroll
  for (int ib = 0; ib < 8; ++ib) {
    const int b = tb * 8 + ib;
    unsigned long long best = 0ull;
#pragma unroll
    for (int iv = 0; iv < 8; ++iv) {
      int v = vbase + tv * 8 + iv;
      if (v >= VOCAB) continue;
      unsigned long long cand = gumbel_pack(acc[iv][ib] + out_b[v], key0, key1, b, v);
      if (cand > best) best = cand;
    }
#pragma unroll
    for (int off = 1; off < 8; off <<= 1) {
      unsigned long long other = __shfl_xor(best, off, 64);
      if (other > best) best = other;
    }
    if (tv == 0) atomicMax(&slot[b], best);
  }
}

// ---------------- token extraction + emb gather/split ----------------
__global__ void k_tok2(const unsigned long long* __restrict__ slot,
                       const float* __restrict__ emb_w,
                       int* __restrict__ tok_next, float* __restrict__ y_out,
                       _Float16* __restrict__ xc_hi, _Float16* __restrict__ xc_lo,
                       int t, int full) {
  const int b = blockIdx.x;
  const int c = threadIdx.x;   // 128 threads
  unsigned long long p = slot[b];
  uint32_t v = ~((uint32_t)(p & 0xFFFFFFFFull));
  if (c == 0) {
    tok_next[b] = (int)v;
    y_out[b * SEQ + t] = (float)v;
  }
  if (!full) return;
  if (c < 75) {
    float4 xv = *(const float4*)&emb_w[(size_t)v * EMB + c * 4];
    half4 hi, lo;
    hl16 r0 = split16(xv.x, 8.0f); hi[0] = r0.hi; lo[0] = r0.lo;
    hl16 r1 = split16(xv.y, 8.0f); hi[1] = r1.hi; lo[1] = r1.lo;
    hl16 r2 = split16(xv.z, 8.0f); hi[2] = r2.hi; lo[2] = r2.lo;
    hl16 r3 = split16(xv.w, 8.0f); hi[3] = r3.hi; lo[3] = r3.lo;
    *(half4*)&xc_hi[b * KIH + c * 4] = hi;
    *(half4*)&xc_lo[b * KIH + c * 4] = lo;
  } else if (c < 80) {
    *(half4*)&xc_hi[b * KIH + c * 4] = (half4)(_Float16)0.0f;
    *(half4*)&xc_lo[b * KIH + c * 4] = (half4)(_Float16)0.0f;
  }
}

// ---------------- host launch ----------------
extern "C" void kernel_launch(void* const* d_in, const int* in_sizes, int n_in,
                              void* d_out, int out_size, void* d_ws, size_t ws_size,
                              hipStream_t stream) {
  const float* z      = (const float*)d_in[0];
  const int*   l      = (const int*)  d_in[1];
  const float* emb_w  = (const float*)d_in[2];
  const float* attr_w = (const float*)d_in[3];
  const float* W_ih   = (const float*)d_in[4];
  const float* W_hh   = (const float*)d_in[5];
  const float* b_ih   = (const float*)d_in[6];
  const float* b_hh   = (const float*)d_in[7];
  const float* out_w  = (const float*)d_in[8];
  const float* out_b  = (const float*)d_in[9];

  float* hy    = (float*)d_out;
  float* y_out = (float*)d_out + HY_ELEMS;

  char* ws = (char*)d_ws;
  size_t off = 0;
  uint32_t* keys            = (uint32_t*)(ws + off);           off += 256;
  unsigned long long* slots = (unsigned long long*)(ws + off); off += (size_t)MAXLEN * B * 8;
  int* tokbuf               = (int*)(ws + off);                off += (size_t)32 * B * 4;
  float* hbuf               = (float*)(ws + off);              off += (size_t)2 * B * HID * 4;
  float* gi                 = (float*)(ws + off);              off += (size_t)B * G3 * 4;
  float* gh                 = (float*)(ws + off);              off += (size_t)B * G3 * 4;
  _Float16* h_hi            = (_Float16*)(ws + off);           off += (size_t)B * KP * 2;
  _Float16* h_lo            = (_Float16*)(ws + off);           off += (size_t)B * KP * 2;
  _Float16* ht              = (_Float16*)(ws + off);           off += (size_t)2 * TILE_STRIDE * 2;
  _Float16* wt              = (_Float16*)(ws + off);           off += (size_t)NVT * TILE_STRIDE * 2;
  const size_t tier1_end = off;
  _Float16* wih_hi          = (_Float16*)(ws + off);           off += (size_t)MPAD * KIH * 2;
  _Float16* wih_lo          = (_Float16*)(ws + off);           off += (size_t)MPAD * KIH * 2;
  _Float16* whh_hi          = (_Float16*)(ws + off);           off += (size_t)MPAD * KP * 2;
  _Float16* whh_lo          = (_Float16*)(ws + off);           off += (size_t)MPAD * KP * 2;
  _Float16* x0_hi           = (_Float16*)(ws + off);           off += (size_t)B * KIH * 2;
  _Float16* x0_lo           = (_Float16*)(ws + off);           off += (size_t)B * KIH * 2;
  _Float16* xe_hi           = (_Float16*)(ws + off);           off += (size_t)B * KIH * 2;
  _Float16* xe_lo           = (_Float16*)(ws + off);           off += (size_t)B * KIH * 2;
  _Float16* xc_hi           = (_Float16*)(ws + off);           off += (size_t)B * KIH * 2;
  _Float16* xc_lo           = (_Float16*)(ws + off);           off += (size_t)B * KIH * 2;
  const size_t tier2_end = off;
  const int tier = (ws_size >= tier2_end) ? 2 : ((ws_size >= tier1_end) ? 1 : 0);

  k_init<<<(B * HID + 255) / 256, 256, 0, stream>>>(
      z, l, attr_w, emb_w, hbuf, keys, slots, tokbuf, y_out, h_hi, h_lo, ht,
      x0_hi, x0_lo, xe_hi, xe_lo, (tier == 2) ? 1 : 0);

  if (tier >= 1) {
    size_t tot = (size_t)VPAD * (KP / 4);
    k_wsplit<<<(int)((tot + 255) / 256), 256, 0, stream>>>(out_w, wt);
  }
  if (tier == 2) {
    int tih = MPAD * KIH / 4, thh = MPAD * KP / 4;
    k_gwsplit<<<(tih + 255) / 256, 256, 0, stream>>>(W_ih, wih_hi, wih_lo, G3, EMB, KIH, tih);
    k_gwsplit<<<(thh + 255) / 256, 256, 0, stream>>>(W_hh, whh_hi, whh_lo, G3, HID, KP, thh);
  }

  for (int t = 0; t <= MAXLEN; ++t) {
    float* hprev = hbuf + (t % 2) * B * HID;
    float* hnext = hbuf + ((t + 1) % 2) * B * HID;

    if (tier == 2) {
      const _Float16* xh = (t == 0) ? x0_hi : ((t == MAXLEN) ? xe_hi : xc_hi);
      const _Float16* xl = (t == 0) ? x0_lo : ((t == MAXLEN) ? xe_lo : xc_lo);
      dim3 g2(33, 4, 2);
      k_gates2<<<g2, 256, 0, stream>>>(wih_hi, wih_lo, whh_hi, whh_lo,
                                       xh, xl, h_hi, h_lo, gi, gh);
    } else {
      const int* tok_t = tokbuf + ((t == MAXLEN) ? 31 : t) * B;
      dim3 ggrid(66, 8, 2);
      k_gates<<<ggrid, 256, 0, stream>>>(W_ih, W_hh, emb_w, hprev, tok_t, gi, gh);
    }
    k_hnew<<<(B * HID + 255) / 256, 256, 0, stream>>>(gi, gh, b_ih, b_hh, hprev,
                                                      hnext, hy, h_hi, h_lo, ht, t);
    if (t < MAXLEN) {
      if (tier >= 1) {
        k_logits10<<<NBLK5, 256, 0, stream>>>(wt, ht, out_b, keys,
                                              slots + (size_t)t * B, t);
      } else {
        k_logits_f32<<<(VOCAB + 63) / 64, 256, 0, stream>>>(hnext, out_w, out_b, keys,
                                                            slots + (size_t)t * B, t);
      }
      k_tok2<<<B, 128, 0, stream>>>(slots + (size_t)t * B, emb_w,
                                    tokbuf + (t + 1) * B, y_out, xc_hi, xc_lo,
                                    t, (tier == 2) ? 1 : 0);
    }
  }
}

// Round 15
// 3514.021 us; speedup vs baseline: 1.0900x; 1.0137x over previous
//
#include <hip/hip_runtime.h>
#include <stdint.h>

#define VOCAB 50257
#define B 256
#define EMB 300
#define HID 700
#define G3 2100          // 3*HID
#define ZDIM 500
#define ATTR_EMBD 200
#define MAXLEN 30
#define SEQ 31           // MAXLEN+1
#define HY_ELEMS (B*SEQ*HID)
#define KP 704           // HID padded to mult of 32
#define NKT 22           // KP/32 k-tiles
#define KIH 320          // EMB padded to mult of 32
#define VPAD 50304       // VOCAB padded to mult of 128 (393*128)
#define NVT 393          // VPAD/128
#define MPAD 2112        // G3 padded to 33*64
#define SOS_IDX 1
#define EOS_IDX 2
// tiled chunk: per (tile, kt): [part(2)][4096 halves]; half idx = (kc*128+row)*8+e
#define CHUNK 4096
#define TILE_STRIDE ((size_t)NKT * 2 * CHUNK)   // halves per v-panel / h half-tile
// logits grid: items = (panel, v-half, b-half) = 393*2*2 = 1572; 8 XCD x 197
#define NIT5 1572
#define NBLK5 1576

typedef _Float16 half8 __attribute__((ext_vector_type(8)));
typedef _Float16 half4 __attribute__((ext_vector_type(4)));
typedef float f32x4 __attribute__((ext_vector_type(4)));

// ---------------- global_load_lds helper (16B per lane, dest = wave base + lane*16)
typedef const __attribute__((address_space(1))) void* gas1_t;
typedef __attribute__((address_space(3))) void* las3_t;
__device__ __forceinline__ void gload_lds16(const void* g, void* l) {
  __builtin_amdgcn_global_load_lds((gas1_t)g, (las3_t)l, 16, 0, 0);
}

// ---------------- threefry2x32 (JAX-exact, 20 rounds) ----------------
__device__ __forceinline__ uint32_t rotl32(uint32_t x, int r) {
  return (x << r) | (x >> (32 - r));
}

__device__ __forceinline__ void threefry2x32(uint32_t k0, uint32_t k1,
                                             uint32_t x0, uint32_t x1,
                                             uint32_t& o0, uint32_t& o1) {
  const uint32_t ks2 = k0 ^ k1 ^ 0x1BD11BDAu;
  x0 += k0; x1 += k1;
#define TF_R4(a, b, c, d)                                     \
  x0 += x1; x1 = rotl32(x1, a); x1 ^= x0;                     \
  x0 += x1; x1 = rotl32(x1, b); x1 ^= x0;                     \
  x0 += x1; x1 = rotl32(x1, c); x1 ^= x0;                     \
  x0 += x1; x1 = rotl32(x1, d); x1 ^= x0;
  TF_R4(13, 15, 26, 6)  x0 += k1;  x1 += ks2 + 1u;
  TF_R4(17, 29, 16, 24) x0 += ks2; x1 += k0 + 2u;
  TF_R4(13, 15, 26, 6)  x0 += k0;  x1 += k1 + 3u;
  TF_R4(17, 29, 16, 24) x0 += k1;  x1 += ks2 + 4u;
  TF_R4(13, 15, 26, 6)  x0 += ks2; x1 += k0 + 5u;
#undef TF_R4
  o0 = x0; o1 = x1;
}

__device__ __forceinline__ unsigned long long gumbel_pack(float s, uint32_t key0,
                                                          uint32_t key1, int b, int v) {
  uint32_t j = (uint32_t)(b * VOCAB + v);
  uint32_t o0, o1;
  threefry2x32(key0, key1, 0u, j, o0, o1);
  uint32_t bits = o0 ^ o1;
  float f = __uint_as_float((bits >> 9) | 0x3f800000u) - 1.0f;
  float u = fmaxf(f, 1.17549435e-38f);
  float g = -__logf(-__logf(u));
  s += g;
  uint32_t us = __float_as_uint(s);
  us = (us & 0x80000000u) ? ~us : (us | 0x80000000u);
  return ((unsigned long long)us << 32) | (uint32_t)(~(uint32_t)v);
}

// split helper: val*scale -> {fp16 hi, fp16 lo = raw residual (UNSCALED)}.
struct hl16 { _Float16 hi, lo; };
__device__ __forceinline__ hl16 split16(float val, float scale) {
  float s = val * scale;
  _Float16 h = (_Float16)s;
  hl16 r;
  r.hi = h;
  r.lo = (_Float16)(s - (float)h);
  return r;
}

// ---------------- init ----------------
__global__ void k_init(const float* __restrict__ z, const int* __restrict__ l,
                       const float* __restrict__ attr_w, const float* __restrict__ emb_w,
                       float* __restrict__ hbuf0, uint32_t* __restrict__ keys,
                       unsigned long long* __restrict__ slots,
                       int* __restrict__ tok, float* __restrict__ y_out,
                       _Float16* __restrict__ h_hi, _Float16* __restrict__ h_lo,
                       _Float16* __restrict__ ht,
                       _Float16* __restrict__ x0_hi, _Float16* __restrict__ x0_lo,
                       _Float16* __restrict__ xe_hi, _Float16* __restrict__ xe_lo,
                       int full) {
  int idx = blockIdx.x * blockDim.x + threadIdx.x;
  if (idx < B * HID) {
    int b = idx / HID, i = idx % HID;
    float v = (i < ZDIM) ? z[b * ZDIM + i]
                         : attr_w[l[b] * ATTR_EMBD + (i - ZDIM)];
    hbuf0[idx] = v;
    hl16 r = split16(v, 8.0f);
    h_hi[b * KP + i] = r.hi;
    h_lo[b * KP + i] = r.lo;
  }
  if (idx < MAXLEN) {
    uint32_t o0, o1;
    threefry2x32(0u, 42u, 0u, (uint32_t)idx, o0, o1);
    keys[2 * idx] = o0; keys[2 * idx + 1] = o1;
  }
  if (idx < MAXLEN * B) slots[idx] = 0ull;
  if (idx < B) {
    tok[idx] = SOS_IDX;
    tok[31 * B + idx] = EOS_IDX;
    y_out[idx * SEQ + MAXLEN] = 2.0f;
  }
  if (idx < B * 4) {  // zero k-pad (700..703) of linear + tiled h (kt=21, kc=3)
    int b = idx >> 2, k = HID + (idx & 3);
    h_hi[b * KP + k] = (_Float16)0.0f;
    h_lo[b * KP + k] = (_Float16)0.0f;
    int c = b >> 7, row = b & 127, e = k & 7;
    size_t tb = (size_t)c * TILE_STRIDE + (size_t)21 * 2 * CHUNK
              + (3 * 128 + row) * 8 + e;
    ht[tb] = (_Float16)0.0f;
    ht[tb + CHUNK] = (_Float16)0.0f;
  }
  if (full && idx < KIH) {
    float v0 = (idx < EMB) ? emb_w[SOS_IDX * EMB + idx] : 0.0f;
    float ve = (idx < EMB) ? emb_w[EOS_IDX * EMB + idx] : 0.0f;
    hl16 r0 = split16(v0, 8.0f);
    hl16 re = split16(ve, 8.0f);
    for (int b = 0; b < B; ++b) {  // broadcast rows (all batches share SOS/EOS)
      x0_hi[b * KIH + idx] = r0.hi; x0_lo[b * KIH + idx] = r0.lo;
      xe_hi[b * KIH + idx] = re.hi; xe_lo[b * KIH + idx] = re.lo;
    }
  }
}

// ---------------- logits w split v3: coalesced read AND write via LDS tile ----
// One block per (panel, kt): read the 128x32 f32 sub-tile (128B segments per
// row), split into the exact chunk layout in LDS (16KB), then stream out
// 2x8KB fully contiguous. r14's direct version wrote scattered 8B fragments
// -> 239MB WRITE_SIZE (RMW amplification); this writes the minimal 141MB.
__global__ __launch_bounds__(256)
void k_wsplit(const float* __restrict__ out_w, _Float16* __restrict__ wt) {
  __shared__ _Float16 sh[2][CHUNK];
  const int bid = blockIdx.x;            // NVT*NKT blocks
  const int p = bid / NKT, kt = bid % NKT;
  const int tid = threadIdx.x;
#pragma unroll
  for (int i = 0; i < 4; ++i) {
    int idx = i * 256 + tid;             // 0..1023
    int row = idx >> 3, k4 = idx & 7;
    int v = p * 128 + row;
    int k = kt * 32 + k4 * 4;
    float x[4];
    if (v < VOCAB && k + 3 < HID) {
      const float4 xv = *(const float4*)&out_w[(size_t)v * HID + k];
      x[0] = xv.x; x[1] = xv.y; x[2] = xv.z; x[3] = xv.w;
    } else {
#pragma unroll
      for (int j = 0; j < 4; ++j)
        x[j] = (v < VOCAB && k + j < HID) ? out_w[(size_t)v * HID + k + j] : 0.0f;
    }
    half4 hi, lo;
#pragma unroll
    for (int j = 0; j < 4; ++j) {
      hl16 r = split16(x[j], 64.0f);
      hi[j] = r.hi; lo[j] = r.lo;
    }
    int kc = k4 >> 1, e0 = (k4 & 1) * 4;
    int ho = (kc * 128 + row) * 8 + e0;
    *(half4*)&sh[0][ho] = hi;
    *(half4*)&sh[1][ho] = lo;
  }
  __syncthreads();
  _Float16* dst = wt + (size_t)p * TILE_STRIDE + (size_t)kt * 2 * CHUNK;
#pragma unroll
  for (int i = 0; i < 2; ++i) {
    int idx = i * 256 + tid;             // 0..511 float4 slots per chunk
    *(float4*)&dst[idx * 8] = *(const float4*)&sh[0][idx * 8];
    *(float4*)&dst[CHUNK + idx * 8] = *(const float4*)&sh[1][idx * 8];
  }
}

// ---------------- generic gate-weight split (Msrc x Ksrc -> MPAD x Kpad) ----------------
__global__ void k_gwsplit(const float* __restrict__ src, _Float16* __restrict__ hi,
                          _Float16* __restrict__ lo, int Msrc, int Ksrc, int Kpad,
                          int tot4) {
  int idx = blockIdx.x * blockDim.x + threadIdx.x;
  if (idx >= tot4) return;
  size_t i4 = (size_t)idx * 4;
  int m = (int)(i4 / Kpad), k = (int)(i4 % Kpad);
  half4 h, l;
#pragma unroll
  for (int j = 0; j < 4; ++j) {
    float x = (m < Msrc && k + j < Ksrc) ? src[(size_t)m * Ksrc + k + j] : 0.0f;
    hl16 r = split16(x, 64.0f);
    h[j] = r.hi; l[j] = r.lo;
  }
  *(half4*)&hi[i4] = h;
  *(half4*)&lo[i4] = l;
}

// ---------------- MFMA gates: 64j x 64b blocks, 4 waves (32x32), merged acc ----
__global__ __launch_bounds__(256, 4)
void k_gates2(const _Float16* __restrict__ wih_hi, const _Float16* __restrict__ wih_lo,
              const _Float16* __restrict__ whh_hi, const _Float16* __restrict__ whh_lo,
              const _Float16* __restrict__ x_hi, const _Float16* __restrict__ x_lo,
              const _Float16* __restrict__ h_hi, const _Float16* __restrict__ h_lo,
              float* __restrict__ gi, float* __restrict__ gh) {
  const int zz = blockIdx.z;
  const _Float16* __restrict__ Whi = zz ? whh_hi : wih_hi;
  const _Float16* __restrict__ Wlo = zz ? whh_lo : wih_lo;
  const _Float16* __restrict__ Xhi = zz ? h_hi : x_hi;
  const _Float16* __restrict__ Xlo = zz ? h_lo : x_lo;
  const int Kz = zz ? KP : KIH;
  float* __restrict__ out = zz ? gh : gi;

  const int jbase = blockIdx.x * 64;
  const int bbase = blockIdx.y * 64;
  __shared__ float4 lds[2][4][256];   // [buf][whi,wlo,xhi,xlo][kc*64+row]
  const int tid = threadIdx.x, lane = tid & 63, wid = tid >> 6;
  const int wj = wid >> 1, wb2 = wid & 1;
  const size_t wrow = (size_t)(jbase + lane) * Kz;   // stage: kc=wid, row=lane
  const size_t xrow = (size_t)(bbase + lane) * Kz;

  f32x4 acc[2][2];
#pragma unroll
  for (int i = 0; i < 2; ++i)
#pragma unroll
    for (int j = 0; j < 2; ++j) acc[i][j] = (f32x4)0.0f;

#define GSTAGE(bf, k0)                                                   \
  {                                                                      \
    gload_lds16(Whi + wrow + (k0) + wid * 8, &lds[bf][0][wid * 64]);     \
    gload_lds16(Wlo + wrow + (k0) + wid * 8, &lds[bf][1][wid * 64]);     \
    gload_lds16(Xhi + xrow + (k0) + wid * 8, &lds[bf][2][wid * 64]);     \
    gload_lds16(Xlo + xrow + (k0) + wid * 8, &lds[bf][3][wid * 64]);     \
  }

  const int nt = Kz / 32;
  GSTAGE(0, 0)
  for (int kt = 0; kt < nt; ++kt) {
    const int cur = kt & 1;
    __syncthreads();                       // drains staged loads for buf[cur]
    if (kt + 1 < nt) GSTAGE(cur ^ 1, (kt + 1) * 32)
    const int kcf = (lane >> 4) * 64 + (lane & 15);
    half8 a_hi[2], a_lo[2];
#pragma unroll
    for (int fv = 0; fv < 2; ++fv) {
      int s = kcf + wj * 32 + fv * 16;
      a_hi[fv] = *(const half8*)&lds[cur][0][s];
      a_lo[fv] = *(const half8*)&lds[cur][1][s];
    }
#pragma unroll
    for (int fb = 0; fb < 2; ++fb) {
      int s = kcf + wb2 * 32 + fb * 16;
      half8 b_hi = *(const half8*)&lds[cur][2][s];
      half8 b_lo = *(const half8*)&lds[cur][3][s];
#pragma unroll
      for (int fv = 0; fv < 2; ++fv) {
        acc[fv][fb] = __builtin_amdgcn_mfma_f32_16x16x32_f16(a_hi[fv], b_hi,
                                                             acc[fv][fb], 0, 0, 0);
        acc[fv][fb] = __builtin_amdgcn_mfma_f32_16x16x32_f16(a_hi[fv], b_lo,
                                                             acc[fv][fb], 0, 0, 0);
        acc[fv][fb] = __builtin_amdgcn_mfma_f32_16x16x32_f16(a_lo[fv], b_hi,
                                                             acc[fv][fb], 0, 0, 0);
      }
    }
  }
#undef GSTAGE

  const float c2 = 1.0f / 512.0f;
#pragma unroll
  for (int fb = 0; fb < 2; ++fb) {
    const int b = bbase + wb2 * 32 + fb * 16 + (lane & 15);
#pragma unroll
    for (int fv = 0; fv < 2; ++fv) {
#pragma unroll
      for (int r = 0; r < 4; ++r) {
        int j = jbase + wj * 32 + fv * 16 + (lane >> 4) * 4 + r;
        if (j < G3) out[b * G3 + j] = acc[fv][fb][r] * c2;
      }
    }
  }
}

// ---------------- fp32 gates fallback ----------------
__global__ void k_gates(const float* __restrict__ W_ih, const float* __restrict__ W_hh,
                        const float* __restrict__ emb_w, const float* __restrict__ hprev,
                        const int* __restrict__ tok,
                        float* __restrict__ gi, float* __restrict__ gh) {
  const int zz = blockIdx.z;
  const float* __restrict__ W = zz ? W_hh : W_ih;
  const int K = zz ? HID : EMB;
  float* __restrict__ out = zz ? gh : gi;
  __shared__ float w_lds[20][36];
  __shared__ float xh_lds[20][36];
  const int jbase = blockIdx.x * 32;
  const int bbase = blockIdx.y * 32;
  const int tid = threadIdx.x;
  const int tj = tid % 16, tb = tid / 16;
  float a00 = 0.f, a01 = 0.f, a10 = 0.f, a11 = 0.f;
  for (int k0 = 0; k0 < K; k0 += 20) {
    for (int idx = tid; idx < 640; idx += 256) {
      int col = idx / 20, kk = idx % 20;
      int j = jbase + col;
      w_lds[kk][col] = (j < G3) ? W[j * K + k0 + kk] : 0.0f;
      int b = bbase + col;
      float xv;
      if (zz) xv = hprev[b * HID + k0 + kk];
      else    xv = emb_w[tok[b] * EMB + k0 + kk];
      xh_lds[kk][col] = xv;
    }
    __syncthreads();
#pragma unroll
    for (int kk = 0; kk < 20; ++kk) {
      float w0 = w_lds[kk][tj * 2], w1 = w_lds[kk][tj * 2 + 1];
      float h0 = xh_lds[kk][tb * 2], h1 = xh_lds[kk][tb * 2 + 1];
      a00 += w0 * h0; a01 += w0 * h1;
      a10 += w1 * h0; a11 += w1 * h1;
    }
    __syncthreads();
  }
  int j0 = jbase + tj * 2, b0 = bbase + tb * 2;
  if (j0 < G3)     { out[b0 * G3 + j0] = a00;     out[(b0 + 1) * G3 + j0] = a01; }
  if (j0 + 1 < G3) { out[b0 * G3 + j0 + 1] = a10; out[(b0 + 1) * G3 + j0 + 1] = a11; }
}

// ---------------- pointwise GRU update + h fp16-split (linear for gates, tiled for logits)
__global__ void k_hnew(const float* __restrict__ gi, const float* __restrict__ gh,
                       const float* __restrict__ b_ih, const float* __restrict__ b_hh,
                       const float* __restrict__ hprev, float* __restrict__ hnext,
                       float* __restrict__ hy, _Float16* __restrict__ h_hi,
                       _Float16* __restrict__ h_lo, _Float16* __restrict__ ht, int t) {
  int idx = blockIdx.x * blockDim.x + threadIdx.x;
  if (idx >= B * HID) return;
  int b = idx / HID, i = idx % HID;
  float ir = gi[b * G3 + i]            + b_ih[i];
  float iz = gi[b * G3 + HID + i]      + b_ih[HID + i];
  float in_ = gi[b * G3 + 2 * HID + i] + b_ih[2 * HID + i];
  float hr = gh[b * G3 + i]            + b_hh[i];
  float hz = gh[b * G3 + HID + i]      + b_hh[HID + i];
  float hn = gh[b * G3 + 2 * HID + i]  + b_hh[2 * HID + i];
  float r  = 1.0f / (1.0f + expf(-(ir + hr)));
  float zg = 1.0f / (1.0f + expf(-(iz + hz)));
  float n  = tanhf(in_ + r * hn);
  float h  = (1.0f - zg) * n + zg * hprev[idx];
  hnext[idx] = h;
  hy[(size_t)b * SEQ * HID + (size_t)t * HID + i] = h;
  hl16 rr = split16(h, 8.0f);
  h_hi[b * KP + i] = rr.hi;
  h_lo[b * KP + i] = rr.lo;
  // tiled image for k_logits10: c=b>>7 (128-row halves), row=b&127,
  // kt=i>>5, kc=(i>>3)&3, e=i&7
  int c = b >> 7, row = b & 127;
  size_t tb = (size_t)c * TILE_STRIDE + (size_t)(i >> 5) * 2 * CHUNK
            + ((((i >> 3) & 3) * 128 + row) * 8) + (i & 7);
  ht[tb] = rr.hi;
  ht[tb + CHUNK] = rr.lo;
}

// ---------------- MFMA logits v11: SAFE counted vmcnt(8) + 3 blocks/CU ----
// (passing r14 kernel, unchanged)
__global__ __launch_bounds__(256, 3)
void k_logits10(const _Float16* __restrict__ wt, const _Float16* __restrict__ ht,
                const float* __restrict__ out_b, const uint32_t* __restrict__ keys,
                unsigned long long* __restrict__ slot, int t) {
  const int item = (blockIdx.x & 7) * 197 + (blockIdx.x >> 3);  // XCD-chunked
  if (item >= NIT5) return;
  const int p = item >> 2, vh = (item >> 1) & 1, c = item & 1;

  __shared__ float4 ldsh[3][1024];   // [buf][part*512 + kc*128 + row]
  const int tid = threadIdx.x, lane = tid & 63, wid = tid >> 6;
  const int wv = wid >> 1, wb = wid & 1;
  const int lq = lane >> 4, lr = lane & 15;

  const _Float16* __restrict__ wp = wt + (size_t)p * TILE_STRIDE;
  const _Float16* __restrict__ hp = ht + (size_t)c * TILE_STRIDE;

  const int wslot = lq * 128 + vh * 64 + wv * 32 + lr;   // + fv*16
  const int hslot = lq * 128 + wb * 64 + lr;             // + fb*16 (+part*512)
  const int vbase0 = p * 128 + vh * 64 + wv * 32;
  const int bbase0 = c * 128 + wb * 64 + lr;
  const uint32_t key0 = keys[2 * t], key1 = keys[2 * t + 1];

  // out_b values for this lane's 8 distinct v (fv x r), reused across fb
  float ob[8];
#pragma unroll
  for (int fv = 0; fv < 2; ++fv)
#pragma unroll
    for (int r = 0; r < 4; ++r) {
      int v = vbase0 + fv * 16 + lq * 4 + r;
      ob[fv * 4 + r] = (v < VOCAB) ? out_b[v] : 0.0f;
    }

  f32x4 acc[2][4];
#pragma unroll
  for (int i = 0; i < 2; ++i)
#pragma unroll
    for (int j = 0; j < 4; ++j) acc[i][j] = (f32x4)0.0f;

  float q[32];          // per-sample out_b + gumbel; ALL indices compile-time
  half8 W0[4], W1[4], W2[4];

#define LOADW(W, ktv)                                                         \
  {                                                                           \
    const _Float16* bw = wp + (size_t)(ktv) * (2 * CHUNK);                    \
    _Pragma("unroll")                                                         \
    for (int fv = 0; fv < 2; ++fv) {                                          \
      W[fv * 2 + 0] = *(const half8*)(bw + (wslot + fv * 16) * 8);            \
      W[fv * 2 + 1] = *(const half8*)(bw + CHUNK + (wslot + fv * 16) * 8);    \
    }                                                                         \
  }
#define STAGEH(bf, ktv)                                                       \
  {                                                                           \
    const _Float16* bh = hp + (size_t)(ktv) * (2 * CHUNK);                    \
    _Pragma("unroll")                                                         \
    for (int j = 0; j < 4; ++j)                                               \
      gload_lds16(bh + (j * 256 + wid * 64 + lane) * 8,                       \
                  &ldsh[bf][j * 256 + wid * 64]);                             \
  }
#define MFMAB(W, BF)                                                          \
  _Pragma("unroll")                                                           \
  for (int fb = 0; fb < 4; ++fb) {                                            \
    half8 hhi = *(const half8*)&ldsh[BF][hslot + fb * 16];                    \
    half8 hlo = *(const half8*)&ldsh[BF][512 + hslot + fb * 16];              \
    _Pragma("unroll")                                                         \
    for (int fv = 0; fv < 2; ++fv) {                                          \
      acc[fv][fb] = __builtin_amdgcn_mfma_f32_16x16x32_f16(                   \
          W[fv * 2 + 0], hhi, acc[fv][fb], 0, 0, 0);                          \
      acc[fv][fb] = __builtin_amdgcn_mfma_f32_16x16x32_f16(                   \
          W[fv * 2 + 0], hlo, acc[fv][fb], 0, 0, 0);                          \
      acc[fv][fb] = __builtin_amdgcn_mfma_f32_16x16x32_f16(                   \
          W[fv * 2 + 1], hhi, acc[fv][fb], 0, 0, 0);                          \
    }                                                                         \
  }
// QS(s): pure-VALU gumbel precompute for sample s (s<32; s==32 -> no-op).
// sample s -> fb=s>>3, fv=(s>>2)&1, r=s&3
#define QS(s)                                                                 \
  if ((s) < 32) {                                                             \
    const int fb_ = (s) >> 3, fv_ = ((s) >> 2) & 1, r_ = (s) & 3;             \
    const int b_ = bbase0 + fb_ * 16;                                         \
    const int v_ = vbase0 + fv_ * 16 + lq * 4 + r_;                           \
    uint32_t o0_, o1_;                                                        \
    threefry2x32(key0, key1, 0u, (uint32_t)(b_ * VOCAB + v_), o0_, o1_);      \
    uint32_t bits_ = o0_ ^ o1_;                                               \
    float f_ = __uint_as_float((bits_ >> 9) | 0x3f800000u) - 1.0f;            \
    float u_ = fmaxf(f_, 1.17549435e-38f);                                    \
    q[(s)] = ob[fv_ * 4 + r_] - __logf(-__logf(u_));                          \
  }
#define STEPN(ktv, BC, BP, WCUR, WNEW, S0, S1, VM)                            \
  {                                                                           \
    asm volatile("s_waitcnt vmcnt(" #VM ")" ::: "memory");                    \
    __builtin_amdgcn_sched_barrier(0);                                        \
    __builtin_amdgcn_s_barrier();                                             \
    __builtin_amdgcn_sched_barrier(0);                                        \
    if ((ktv) + 2 < NKT) {                                                    \
      STAGEH(BP, (ktv) + 2)                                                   \
      LOADW(WNEW, (ktv) + 2)                                                  \
    }                                                                         \
    __builtin_amdgcn_s_setprio(1);                                            \
    MFMAB(WCUR, BC)                                                           \
    __builtin_amdgcn_s_setprio(0);                                            \
    QS(S0)                                                                    \
    QS(S1)                                                                    \
  }

  STAGEH(0, 0)
  STAGEH(1, 1)
  LOADW(W0, 0)
  LOADW(W1, 1)
  STEPN(0, 0, 2, W0, W2, 0, 1, 8)
  STEPN(1, 1, 0, W1, W0, 2, 3, 8)
  STEPN(2, 2, 1, W2, W1, 4, 5, 8)
  STEPN(3, 0, 2, W0, W2, 6, 7, 8)
  STEPN(4, 1, 0, W1, W0, 8, 9, 8)
  STEPN(5, 2, 1, W2, W1, 10, 11, 8)
  STEPN(6, 0, 2, W0, W2, 12, 13, 8)
  STEPN(7, 1, 0, W1, W0, 14, 15, 8)
  STEPN(8, 2, 1, W2, W1, 16, 17, 8)
  STEPN(9, 0, 2, W0, W2, 18, 19, 8)
  STEPN(10, 1, 0, W1, W0, 20, 32, 8)
  STEPN(11, 2, 1, W2, W1, 21, 32, 8)
  STEPN(12, 0, 2, W0, W2, 22, 32, 8)
  STEPN(13, 1, 0, W1, W0, 23, 32, 8)
  STEPN(14, 2, 1, W2, W1, 24, 32, 8)
  STEPN(15, 0, 2, W0, W2, 25, 32, 8)
  STEPN(16, 1, 0, W1, W0, 26, 32, 8)
  STEPN(17, 2, 1, W2, W1, 27, 32, 8)
  STEPN(18, 0, 2, W0, W2, 28, 32, 8)
  STEPN(19, 1, 0, W1, W0, 29, 32, 8)
  STEPN(20, 2, 1, W2, W1, 30, 32, 8)
  STEPN(21, 0, 2, W0, W2, 31, 32, 0)
#undef STEPN
#undef QS
#undef LOADW
#undef STAGEH
#undef MFMAB

  // short epilogue: score = acc*c2 + q; pack; reduce; atomicMax
  const float c2 = 1.0f / 512.0f;
#pragma unroll
  for (int fb = 0; fb < 4; ++fb) {
    const int b = bbase0 + fb * 16;
    unsigned long long best = 0ull;
#pragma unroll
    for (int fv = 0; fv < 2; ++fv) {
#pragma unroll
      for (int r = 0; r < 4; ++r) {
        int v = vbase0 + fv * 16 + lq * 4 + r;
        if (v < VOCAB) {
          float sc = acc[fv][fb][r] * c2 + q[fb * 8 + fv * 4 + r];
          uint32_t us = __float_as_uint(sc);
          us = (us & 0x80000000u) ? ~us : (us | 0x80000000u);
          unsigned long long cand =
              ((unsigned long long)us << 32) | (uint32_t)(~(uint32_t)v);
          if (cand > best) best = cand;
        }
      }
    }
    unsigned long long o;
    o = __shfl_xor(best, 16, 64); if (o > best) best = o;
    o = __shfl_xor(best, 32, 64); if (o > best) best = o;
    if (lq == 0) atomicMax(&slot[b], best);
  }
}

// ---------------- fp32 logits fallback ----------------
#define WPITCH 68
#define HPITCH 260
__global__ __launch_bounds__(256)
void k_logits_f32(const float* __restrict__ h, const float* __restrict__ out_w,
                  const float* __restrict__ out_b, const uint32_t* __restrict__ keys,
                  unsigned long long* __restrict__ slot, int t) {
  __shared__ float w_lds[20][WPITCH];
  __shared__ float h_lds[20][HPITCH];
  const int vbase = blockIdx.x * 64;
  const int tid = threadIdx.x;
  const int tv = tid % 8, tb = tid / 8;
  float acc[8][8];
#pragma unroll
  for (int i = 0; i < 8; ++i)
#pragma unroll
    for (int j = 0; j < 8; ++j) acc[i][j] = 0.f;

  for (int k0 = 0; k0 < HID; k0 += 20) {
    for (int idx = tid; idx < 64 * 20; idx += 256) {
      int vv = idx / 20, kk = idx % 20;
      int v = vbase + vv;
      w_lds[kk][vv] = (v < VOCAB) ? out_w[(size_t)v * HID + k0 + kk] : 0.0f;
    }
    for (int idx = tid; idx < 256 * 20; idx += 256) {
      int bb = idx / 20, kk = idx % 20;
      h_lds[kk][bb] = h[bb * HID + k0 + kk];
    }
    __syncthreads();
#pragma unroll
    for (int kk = 0; kk < 20; ++kk) {
      float wv[8], hv[8];
      *(float4*)&wv[0] = *(const float4*)&w_lds[kk][tv * 8];
      *(float4*)&wv[4] = *(const float4*)&w_lds[kk][tv * 8 + 4];
      *(float4*)&hv[0] = *(const float4*)&h_lds[kk][tb * 8];
      *(float4*)&hv[4] = *(const float4*)&h_lds[kk][tb * 8 + 4];
#pragma unroll
      for (int iv = 0; iv < 8; ++iv)
#pragma unroll
        for (int ib = 0; ib < 8; ++ib) acc[iv][ib] += wv[iv] * hv[ib];
    }
    __syncthreads();
  }

  const uint32_t key0 = keys[2 * t], key1 = keys[2 * t + 1];
#pragma unroll
  for (int ib = 0; ib < 8; ++ib) {
    const int b = tb * 8 + ib;
    unsigned long long best = 0ull;
#pragma unroll
    for (int iv = 0; iv < 8; ++iv) {
      int v = vbase + tv * 8 + iv;
      if (v >= VOCAB) continue;
      unsigned long long cand = gumbel_pack(acc[iv][ib] + out_b[v], key0, key1, b, v);
      if (cand > best) best = cand;
    }
#pragma unroll
    for (int off = 1; off < 8; off <<= 1) {
      unsigned long long other = __shfl_xor(best, off, 64);
      if (other > best) best = other;
    }
    if (tv == 0) atomicMax(&slot[b], best);
  }
}

// ---------------- token extraction + emb gather/split ----------------
__global__ void k_tok2(const unsigned long long* __restrict__ slot,
                       const float* __restrict__ emb_w,
                       int* __restrict__ tok_next, float* __restrict__ y_out,
                       _Float16* __restrict__ xc_hi, _Float16* __restrict__ xc_lo,
                       int t, int full) {
  const int b = blockIdx.x;
  const int c = threadIdx.x;   // 128 threads
  unsigned long long p = slot[b];
  uint32_t v = ~((uint32_t)(p & 0xFFFFFFFFull));
  if (c == 0) {
    tok_next[b] = (int)v;
    y_out[b * SEQ + t] = (float)v;
  }
  if (!full) return;
  if (c < 75) {
    float4 xv = *(const float4*)&emb_w[(size_t)v * EMB + c * 4];
    half4 hi, lo;
    hl16 r0 = split16(xv.x, 8.0f); hi[0] = r0.hi; lo[0] = r0.lo;
    hl16 r1 = split16(xv.y, 8.0f); hi[1] = r1.hi; lo[1] = r1.lo;
    hl16 r2 = split16(xv.z, 8.0f); hi[2] = r2.hi; lo[2] = r2.lo;
    hl16 r3 = split16(xv.w, 8.0f); hi[3] = r3.hi; lo[3] = r3.lo;
    *(half4*)&xc_hi[b * KIH + c * 4] = hi;
    *(half4*)&xc_lo[b * KIH + c * 4] = lo;
  } else if (c < 80) {
    *(half4*)&xc_hi[b * KIH + c * 4] = (half4)(_Float16)0.0f;
    *(half4*)&xc_lo[b * KIH + c * 4] = (half4)(_Float16)0.0f;
  }
}

// ---------------- host launch ----------------
extern "C" void kernel_launch(void* const* d_in, const int* in_sizes, int n_in,
                              void* d_out, int out_size, void* d_ws, size_t ws_size,
                              hipStream_t stream) {
  const float* z      = (const float*)d_in[0];
  const int*   l      = (const int*)  d_in[1];
  const float* emb_w  = (const float*)d_in[2];
  const float* attr_w = (const float*)d_in[3];
  const float* W_ih   = (const float*)d_in[4];
  const float* W_hh   = (const float*)d_in[5];
  const float* b_ih   = (const float*)d_in[6];
  const float* b_hh   = (const float*)d_in[7];
  const float* out_w  = (const float*)d_in[8];
  const float* out_b  = (const float*)d_in[9];

  float* hy    = (float*)d_out;
  float* y_out = (float*)d_out + HY_ELEMS;

  char* ws = (char*)d_ws;
  size_t off = 0;
  uint32_t* keys            = (uint32_t*)(ws + off);           off += 256;
  unsigned long long* slots = (unsigned long long*)(ws + off); off += (size_t)MAXLEN * B * 8;
  int* tokbuf               = (int*)(ws + off);                off += (size_t)32 * B * 4;
  float* hbuf               = (float*)(ws + off);              off += (size_t)2 * B * HID * 4;
  float* gi                 = (float*)(ws + off);              off += (size_t)B * G3 * 4;
  float* gh                 = (float*)(ws + off);              off += (size_t)B * G3 * 4;
  _Float16* h_hi            = (_Float16*)(ws + off);           off += (size_t)B * KP * 2;
  _Float16* h_lo            = (_Float16*)(ws + off);           off += (size_t)B * KP * 2;
  _Float16* ht              = (_Float16*)(ws + off);           off += (size_t)2 * TILE_STRIDE * 2;
  _Float16* wt              = (_Float16*)(ws + off);           off += (size_t)NVT * TILE_STRIDE * 2;
  const size_t tier1_end = off;
  _Float16* wih_hi          = (_Float16*)(ws + off);           off += (size_t)MPAD * KIH * 2;
  _Float16* wih_lo          = (_Float16*)(ws + off);           off += (size_t)MPAD * KIH * 2;
  _Float16* whh_hi          = (_Float16*)(ws + off);           off += (size_t)MPAD * KP * 2;
  _Float16* whh_lo          = (_Float16*)(ws + off);           off += (size_t)MPAD * KP * 2;
  _Float16* x0_hi           = (_Float16*)(ws + off);           off += (size_t)B * KIH * 2;
  _Float16* x0_lo           = (_Float16*)(ws + off);           off += (size_t)B * KIH * 2;
  _Float16* xe_hi           = (_Float16*)(ws + off);           off += (size_t)B * KIH * 2;
  _Float16* xe_lo           = (_Float16*)(ws + off);           off += (size_t)B * KIH * 2;
  _Float16* xc_hi           = (_Float16*)(ws + off);           off += (size_t)B * KIH * 2;
  _Float16* xc_lo           = (_Float16*)(ws + off);           off += (size_t)B * KIH * 2;
  const size_t tier2_end = off;
  const int tier = (ws_size >= tier2_end) ? 2 : ((ws_size >= tier1_end) ? 1 : 0);

  k_init<<<(B * HID + 255) / 256, 256, 0, stream>>>(
      z, l, attr_w, emb_w, hbuf, keys, slots, tokbuf, y_out, h_hi, h_lo, ht,
      x0_hi, x0_lo, xe_hi, xe_lo, (tier == 2) ? 1 : 0);

  if (tier >= 1) {
    k_wsplit<<<NVT * NKT, 256, 0, stream>>>(out_w, wt);
  }
  if (tier == 2) {
    int tih = MPAD * KIH / 4, thh = MPAD * KP / 4;
    k_gwsplit<<<(tih + 255) / 256, 256, 0, stream>>>(W_ih, wih_hi, wih_lo, G3, EMB, KIH, tih);
    k_gwsplit<<<(thh + 255) / 256, 256, 0, stream>>>(W_hh, whh_hi, whh_lo, G3, HID, KP, thh);
  }

  for (int t = 0; t <= MAXLEN; ++t) {
    float* hprev = hbuf + (t % 2) * B * HID;
    float* hnext = hbuf + ((t + 1) % 2) * B * HID;

    if (tier == 2) {
      const _Float16* xh = (t == 0) ? x0_hi : ((t == MAXLEN) ? xe_hi : xc_hi);
      const _Float16* xl = (t == 0) ? x0_lo : ((t == MAXLEN) ? xe_lo : xc_lo);
      dim3 g2(33, 4, 2);
      k_gates2<<<g2, 256, 0, stream>>>(wih_hi, wih_lo, whh_hi, whh_lo,
                                       xh, xl, h_hi, h_lo, gi, gh);
    } else {
      const int* tok_t = tokbuf + ((t == MAXLEN) ? 31 : t) * B;
      dim3 ggrid(66, 8, 2);
      k_gates<<<ggrid, 256, 0, stream>>>(W_ih, W_hh, emb_w, hprev, tok_t, gi, gh);
    }
    k_hnew<<<(B * HID + 255) / 256, 256, 0, stream>>>(gi, gh, b_ih, b_hh, hprev,
                                                      hnext, hy, h_hi, h_lo, ht, t);
    if (t < MAXLEN) {
      if (tier >= 1) {
        k_logits10<<<NBLK5, 256, 0, stream>>>(wt, ht, out_b, keys,
                                              slots + (size_t)t * B, t);
      } else {
        k_logits_f32<<<(VOCAB + 63) / 64, 256, 0, stream>>>(hnext, out_w, out_b, keys,
                                                            slots + (size_t)t * B, t);
      }
      k_tok2<<<B, 128, 0, stream>>>(slots + (size_t)t * B, emb_w,
                                    tokbuf + (t + 1) * B, y_out, xc_hi, xc_lo,
                                    t, (tier == 2) ? 1 : 0);
    }
  }
}